// Round 3
// baseline (351.737 us; speedup 1.0000x reference)
//
#include <hip/hip_runtime.h>
#include <stdint.h>

// ---------------------------------------------------------------------------
// Attention_18116172054662 on MI355X (gfx950)
//   L = tgt @ src^T  (2-term split-f16: (tgt_hi + tgt_lo) @ src_f16)
//   weight = softmax(L, axis=tgt)   -> second output (f32, in place in d_out)
//   out = weight @ PT^T + Q + b  where  PT = W1 @ src^T,  Q = tgt @ W2^T
// R1: global_load_lds width-16 staging, fused column stats, vectorized EW.
// R6: algebraic restructure (PT/Q/final), BK=64 GEMMs.
// R7: XOR chunk swizzle (slot = chunk ^ (row&7)) kills 128B-row bank wrap.
// R8: logits GEMM on 256x256 / 8-wave / dbuf-prefetch template (raw
//     s_barrier, prefetch 1 deep, swizzle: conflicts 6.3M -> 0). 95 -> 83us.
// R9: ported R8 structure to PT/Q/final GEMMs (256x128, BK=64). 358 -> 348.
// R10: drain -> counted waits (T4). 3 LDS buffers, prefetch 2 tiles deep,
//     per-iter s_waitcnt vmcnt(6) (own oldest tile only; barrier makes it
//     collective), stage(kt+2) issued after the barrier. Loads get ~2
//     compute-tiles to land instead of 1 + full drain. Never vmcnt(0) in
//     the steady-state loop.
// ---------------------------------------------------------------------------

#define B_   4
#define S_   2048
#define D_   1024
#define OUTD 1024

typedef unsigned short ushort_t;
typedef _Float16 half8 __attribute__((ext_vector_type(8)));
typedef float    f32x4 __attribute__((ext_vector_type(4)));

__device__ __forceinline__ ushort_t f2h(float f) {
    union { _Float16 h; ushort_t u; } v;
    v.h = (_Float16)f;                    // RNE
    return v.u;
}
__device__ __forceinline__ float h2f(ushort_t u) {
    union { _Float16 h; ushort_t u; } v;
    v.u = u;
    return (float)v.h;
}

// async global->LDS, 16B per lane; LDS dest = wave-uniform base + lane*16
__device__ __forceinline__ void ld16(const ushort_t* g, ushort_t* l) {
    __builtin_amdgcn_global_load_lds(
        (const __attribute__((address_space(1))) void*)g,
        (__attribute__((address_space(3))) void*)l, 16, 0, 0);
}

// --------------------------- elementwise prep ------------------------------

// src -> f16; tgt -> f16 hi + f16 lo
__global__ void k_split(const float4* __restrict__ src, const float4* __restrict__ tgt,
                        ushort4* __restrict__ sh,
                        ushort4* __restrict__ th, ushort4* __restrict__ tl)
{
    const int64_t n4 = (int64_t)B_ * S_ * D_ / 4;
    for (int64_t i = (int64_t)blockIdx.x * blockDim.x + threadIdx.x; i < n4;
         i += (int64_t)gridDim.x * blockDim.x) {
        float4 s = src[i];
        sh[i] = (ushort4){f2h(s.x), f2h(s.y), f2h(s.z), f2h(s.w)};
        float4 tv = tgt[i];
        ushort4 ht = {f2h(tv.x), f2h(tv.y), f2h(tv.z), f2h(tv.w)};
        th[i] = ht;
        tl[i] = (ushort4){f2h(tv.x - h2f(ht.x)), f2h(tv.y - h2f(ht.y)),
                          f2h(tv.z - h2f(ht.z)), f2h(tv.w - h2f(ht.w))};
    }
}

__global__ void k_wconv(const float4* __restrict__ W, ushort4* __restrict__ wb)
{
    const int64_t n4 = (int64_t)OUTD * 2 * D_ / 4;
    for (int64_t i = (int64_t)blockIdx.x * blockDim.x + threadIdx.x; i < n4;
         i += (int64_t)gridDim.x * blockDim.x) {
        float4 w = W[i];
        wb[i] = (ushort4){f2h(w.x), f2h(w.y), f2h(w.z), f2h(w.w)};
    }
}

// ------------------------------- GEMM 1 ------------------------------------
// L[b] = tgt[b] @ src[b]^T, 2-term f16 split:  Ah*B + Al*B
// 256x256 tile, BK=32, 8 waves 4x2 of 64x128, 16x16x32 f16 MFMA.
// Triple-buffered LDS, counted vmcnt(6) + raw s_barrier, prefetch 2 deep.
// LDS layout per 256x32 tile: paired rows -> [128][64] f16, 128B lines,
//   chunk_g = (r&1)*4 + (k>>3); slot = chunk_g ^ ((r>>1)&7); 16B chunks.
// Epilogue: per-block (256-row chunk) column max/sumexp -> pm/ps (8 chunks).
__launch_bounds__(512, 2)
__global__ void k_gemm_logits(const ushort_t* __restrict__ Ah, const ushort_t* __restrict__ Al,
                              const ushort_t* __restrict__ Bs,
                              float* __restrict__ C,
                              float* __restrict__ pm, float* __restrict__ ps)
{
    const int M = S_, N = S_, K = D_;
    int b = blockIdx.z;
    Ah += (int64_t)b * M * K;  Al += (int64_t)b * M * K;
    Bs += (int64_t)b * N * K;
    C  += (int64_t)b * M * N;

    // 3 bufs x { Ah 16KB | Al 16KB | B 16KB }  (ushort units; 144 KiB total)
    __shared__ __align__(16) ushort_t lds[3 * 24576];
    __shared__ float red_m[4][256], red_s[4][256];

    int t    = threadIdx.x;                 // 0..511
    int m0   = blockIdx.y * 256, n0 = blockIdx.x * 256;
    int wave = t >> 6, lane = t & 63;
    int wr   = (wave >> 1) * 64;            // 0,64,128,192
    int wc   = (wave & 1) * 128;            // 0,128
    int l15  = lane & 15, quad = lane >> 4;

    f32x4 acc[4][8];
#pragma unroll
    for (int i = 0; i < 4; i++)
#pragma unroll
        for (int j = 0; j < 8; j++) acc[i][j] = (f32x4){0.f, 0.f, 0.f, 0.f};

    // ---- staging map: thread t writes LDS bytes [t*16, t*16+16) of each
    //      8KB pass (pass covers 64 paired-rows = 128 global rows).
    //      Invert the swizzle on the GLOBAL side; LDS dest stays linear.
    int pr   = t >> 3;                      // paired-row 0..63 within pass
    int slot = t & 7;
    int cg   = slot ^ (pr & 7);
    int srow = pr * 2 + (cg >> 2);          // 0..127 (+128 for pass 1)
    int scol = (cg & 3) * 8;                // f16 col within BK=32

    const ushort_t* gAh = Ah + (int64_t)(m0 + srow) * K + scol;
    const ushort_t* gAl = Al + (int64_t)(m0 + srow) * K + scol;
    const ushort_t* gB  = Bs + (int64_t)(n0 + srow) * K + scol;
    const int64_t rstep = (int64_t)128 * K;     // pass-1 global row offset

    auto stage = [&](int bufi, int kofs) {
        ushort_t* Lb = lds + bufi * 24576 + t * 8;
        ld16(gAh + kofs,         Lb);
        ld16(gAh + rstep + kofs, Lb + 4096);
        ld16(gAl + kofs,         Lb + 8192);
        ld16(gAl + rstep + kofs, Lb + 12288);
        ld16(gB  + kofs,         Lb + 16384);
        ld16(gB  + rstep + kofs, Lb + 20480);
    };

    // ---- ds_read offsets (ushort units within one 16KB tile)
    int aoff[4], boff[8];
#pragma unroll
    for (int i = 0; i < 4; i++) {
        int R = wr + i * 16 + l15;
        int p = R >> 1, c = ((R & 1) << 2) + quad;
        aoff[i] = p * 64 + ((c ^ (p & 7)) << 3);
    }
#pragma unroll
    for (int j = 0; j < 8; j++) {
        int R = wc + j * 16 + l15;
        int p = R >> 1, c = ((R & 1) << 2) + quad;
        boff[j] = p * 64 + ((c ^ (p & 7)) << 3);
    }

    stage(0, 0);                            // prologue: tiles 0 and 1 in flight
    stage(1, 32);
    const int NT = 32;

    for (int kt = 0; kt < NT; ++kt) {
        // own oldest 6 loads (tile kt) done; barrier makes it collective
        if (kt + 1 < NT) {
            asm volatile("s_waitcnt vmcnt(6)" ::: "memory");
        } else {
            asm volatile("s_waitcnt vmcnt(0)" ::: "memory");
        }
        __builtin_amdgcn_s_barrier();
        asm volatile("" ::: "memory");
        __builtin_amdgcn_sched_barrier(0);

        if (kt + 2 < NT) stage((kt + 2) % 3, (kt + 2) * 32);

        const ushort_t* Lb = lds + (kt % 3) * 24576;
        half8 ah[4], al[4], bf[4];
#pragma unroll
        for (int i = 0; i < 4; i++) {
            ah[i] = *(const half8*)(Lb + aoff[i]);
            al[i] = *(const half8*)(Lb + 8192 + aoff[i]);
        }
#pragma unroll
        for (int j = 0; j < 4; j++) bf[j] = *(const half8*)(Lb + 16384 + boff[j]);

        __builtin_amdgcn_s_setprio(1);
#pragma unroll
        for (int i = 0; i < 4; i++)
#pragma unroll
            for (int j = 0; j < 4; j++)
                acc[i][j] = __builtin_amdgcn_mfma_f32_16x16x32_f16(ah[i], bf[j], acc[i][j], 0, 0, 0);
#pragma unroll
        for (int i = 0; i < 4; i++)
#pragma unroll
            for (int j = 0; j < 4; j++)
                acc[i][j] = __builtin_amdgcn_mfma_f32_16x16x32_f16(al[i], bf[j], acc[i][j], 0, 0, 0);
        __builtin_amdgcn_s_setprio(0);

#pragma unroll
        for (int j = 0; j < 4; j++) bf[j] = *(const half8*)(Lb + 16384 + boff[4 + j]);

        __builtin_amdgcn_s_setprio(1);
#pragma unroll
        for (int i = 0; i < 4; i++)
#pragma unroll
            for (int j = 0; j < 4; j++)
                acc[i][4 + j] = __builtin_amdgcn_mfma_f32_16x16x32_f16(ah[i], bf[j], acc[i][4 + j], 0, 0, 0);
#pragma unroll
        for (int i = 0; i < 4; i++)
#pragma unroll
            for (int j = 0; j < 4; j++)
                acc[i][4 + j] = __builtin_amdgcn_mfma_f32_16x16x32_f16(al[i], bf[j], acc[i][4 + j], 0, 0, 0);
        __builtin_amdgcn_s_setprio(0);
    }

    // C store (f32, coalesced per 16 lanes)
#pragma unroll
    for (int i = 0; i < 4; i++) {
        int row_base = m0 + wr + i * 16 + quad * 4;
#pragma unroll
        for (int j = 0; j < 8; j++) {
            int col = n0 + wc + j * 16 + l15;
#pragma unroll
            for (int r = 0; r < 4; r++)
                C[(int64_t)(row_base + r) * N + col] = acc[i][j][r];
        }
    }

    // fused partial column stats (max & sumexp over this block's 256 rows)
    int wrow = wave >> 1;
#pragma unroll
    for (int j = 0; j < 8; j++) {
        float m = -3.0e38f;
#pragma unroll
        for (int i = 0; i < 4; i++)
#pragma unroll
            for (int r = 0; r < 4; r++) m = fmaxf(m, acc[i][j][r]);
        float s = 0.f;
#pragma unroll
        for (int i = 0; i < 4; i++)
#pragma unroll
            for (int r = 0; r < 4; r++) s += __expf(acc[i][j][r] - m);
#pragma unroll
        for (int d = 16; d <= 32; d <<= 1) {
            float m2 = __shfl_xor(m, d, 64);
            float s2 = __shfl_xor(s, d, 64);
            float nm = fmaxf(m, m2);
            s = s * __expf(m - nm) + s2 * __expf(m2 - nm);
            m = nm;
        }
        if (lane < 16) {
            red_m[wrow][wc + j * 16 + l15] = m;
            red_s[wrow][wc + j * 16 + l15] = s;
        }
    }
    __syncthreads();
    if (t < 256) {
        float m = red_m[0][t];
#pragma unroll
        for (int w = 1; w < 4; w++) m = fmaxf(m, red_m[w][t]);
        float s = 0.f;
#pragma unroll
        for (int w = 0; w < 4; w++) s += red_s[w][t] * __expf(red_m[w][t] - m);
        int idx = blockIdx.y * (B_ * S_) + b * S_ + n0 + t;
        pm[idx] = m;
        ps[idx] = s;
    }
}

// --------------------------- column softmax --------------------------------

__global__ void k_colstats2(const float* __restrict__ pm, const float* __restrict__ ps,
                            float* __restrict__ cmax, float* __restrict__ cinv)
{
    int i = blockIdx.x * 256 + threadIdx.x;   // 8192
    float m = -3.0e38f;
#pragma unroll
    for (int c = 0; c < 8; c++) m = fmaxf(m, pm[c * (B_ * S_) + i]);
    float sum = 0.f;
#pragma unroll
    for (int c = 0; c < 8; c++) sum += ps[c * (B_ * S_) + i] * __expf(pm[c * (B_ * S_) + i] - m);
    cmax[i] = m;
    cinv[i] = 1.0f / sum;
}

// weight = exp(L - cmax)/csum, in place; also emit f16 copy for the final GEMM
__global__ void k_softmax_norm(float4* __restrict__ L, const float4* __restrict__ cmax4,
                               const float4* __restrict__ cinv4, ushort4* __restrict__ wbf)
{
    const int64_t n4 = (int64_t)B_ * S_ * S_ / 4;
    for (int64_t i = (int64_t)blockIdx.x * blockDim.x + threadIdx.x; i < n4;
         i += (int64_t)gridDim.x * blockDim.x) {
        int b  = (int)(i >> 20);
        int c4 = (int)(i & 511);
        float4 x  = L[i];
        float4 cm = cmax4[b * 512 + c4];
        float4 ci = cinv4[b * 512 + c4];
        float4 w;
        w.x = __expf(x.x - cm.x) * ci.x;
        w.y = __expf(x.y - cm.y) * ci.y;
        w.z = __expf(x.z - cm.z) * ci.z;
        w.w = __expf(x.w - cm.w) * ci.w;
        L[i] = w;
        wbf[i] = (ushort4){f2h(w.x), f2h(w.y), f2h(w.z), f2h(w.w)};
    }
}

// ------------------ NT f16 GEMM, R10 structure ------------------------------
// C[m][n] = sum_k A[m][k]*B[n][k].  256x128 tile, BK=64, 8 waves 4x2 of
// 64x64, 16x16x32 f16 MFMA.  Triple-buffered LDS (144KB), counted vmcnt(6)
// + raw s_barrier per K-tile, prefetch 2 tiles deep, XOR chunk swizzle
// (slot = chunk ^ (row&7)) on GLOBAL side for staging / addresses for reads.
// LDS per tile: A 256x64 (32KB) @0, B 128x64 (16KB) @16384 (ushort units).
__launch_bounds__(512, 2)
__global__ void k_gemm_nt2(const ushort_t* __restrict__ A, int lda, int64_t bsA,
                           const ushort_t* __restrict__ Bm, int ldb, int64_t bsB,
                           ushort_t* __restrict__ C, int ldc, int64_t bsC, int K)
{
    int b = blockIdx.z;
    A  += (int64_t)b * bsA;
    Bm += (int64_t)b * bsB;
    C  += (int64_t)b * bsC;

    __shared__ __align__(16) ushort_t lds[3 * 24576];

    int t    = threadIdx.x;                 // 0..511
    int m0   = blockIdx.y * 256, n0 = blockIdx.x * 128;
    int wave = t >> 6, lane = t & 63;
    int wr   = (wave >> 1) * 64;            // 0,64,128,192
    int wc   = (wave & 1) * 64;             // 0,64
    int l15  = lane & 15, quad = lane >> 4;

    f32x4 acc[4][4];
#pragma unroll
    for (int i = 0; i < 4; i++)
#pragma unroll
        for (int j = 0; j < 4; j++) acc[i][j] = (f32x4){0.f, 0.f, 0.f, 0.f};

    // staging: thread t covers (row = srow + 64*pass, 16B chunk cg) where the
    // swizzle is inverted on the global side; LDS dest linear at t*16B/pass.
    int srow = t >> 3;                      // 0..63
    int cg   = (t & 7) ^ (srow & 7);
    int scol = cg * 8;

    const ushort_t* gA = A  + (int64_t)(m0 + srow) * lda + scol;
    const ushort_t* gB = Bm + (int64_t)(n0 + srow) * ldb + scol;

    auto stage = [&](int bufi, int k0) {
        ushort_t* Lb = lds + bufi * 24576 + t * 8;
        ld16(gA + k0,                        Lb);
        ld16(gA + (int64_t)64  * lda + k0,   Lb + 4096);
        ld16(gA + (int64_t)128 * lda + k0,   Lb + 8192);
        ld16(gA + (int64_t)192 * lda + k0,   Lb + 12288);
        ld16(gB + k0,                        Lb + 16384);
        ld16(gB + (int64_t)64  * ldb + k0,   Lb + 20480);
    };

    // read offsets (ushort units), h = K-half (ks = h*32)
    int aoff[4][2], boff[4][2];
#pragma unroll
    for (int i = 0; i < 4; i++) {
        int R = wr + i * 16 + l15;
#pragma unroll
        for (int h = 0; h < 2; h++) {
            int c = quad + h * 4;
            aoff[i][h] = R * 64 + ((c ^ (R & 7)) << 3);
        }
    }
#pragma unroll
    for (int j = 0; j < 4; j++) {
        int R = wc + j * 16 + l15;
#pragma unroll
        for (int h = 0; h < 2; h++) {
            int c = quad + h * 4;
            boff[j][h] = 16384 + R * 64 + ((c ^ (R & 7)) << 3);
        }
    }

    const int NT = K >> 6;
    stage(0, 0);
    stage(1, 64);

    for (int kt = 0; kt < NT; ++kt) {
        if (kt + 1 < NT) {
            asm volatile("s_waitcnt vmcnt(6)" ::: "memory");
        } else {
            asm volatile("s_waitcnt vmcnt(0)" ::: "memory");
        }
        __builtin_amdgcn_s_barrier();
        asm volatile("" ::: "memory");
        __builtin_amdgcn_sched_barrier(0);

        if (kt + 2 < NT) stage((kt + 2) % 3, (kt + 2) * 64);

        const ushort_t* Lb = lds + (kt % 3) * 24576;
#pragma unroll
        for (int h = 0; h < 2; h++) {
            half8 af[4], bf[4];
#pragma unroll
            for (int i = 0; i < 4; i++) af[i] = *(const half8*)(Lb + aoff[i][h]);
#pragma unroll
            for (int j = 0; j < 4; j++) bf[j] = *(const half8*)(Lb + boff[j][h]);
            __builtin_amdgcn_s_setprio(1);
#pragma unroll
            for (int i = 0; i < 4; i++)
#pragma unroll
                for (int j = 0; j < 4; j++)
                    acc[i][j] = __builtin_amdgcn_mfma_f32_16x16x32_f16(af[i], bf[j], acc[i][j], 0, 0, 0);
            __builtin_amdgcn_s_setprio(0);
        }
    }

#pragma unroll
    for (int i = 0; i < 4; i++) {
        int row_base = m0 + wr + i * 16 + quad * 4;
#pragma unroll
        for (int j = 0; j < 4; j++) {
            int col = n0 + wc + j * 16 + l15;
#pragma unroll
            for (int r = 0; r < 4; r++)
                C[(int64_t)(row_base + r) * ldc + col] = f2h(acc[i][j][r]);
        }
    }
}

// --------------------------- final GEMM (R10) -------------------------------
// out[b][t][n] = sum_s weight_f16[b][t][s]*PT[b][n][s] + Q[b][t][n] + bias[n]
// Same 256x128 / BK=64 / 8-wave 3-buf counted structure; f32 out + Q + bias.
__launch_bounds__(512, 2)
__global__ void k_gemm_final(const ushort_t* __restrict__ Wt, const ushort_t* __restrict__ PT,
                             const ushort_t* __restrict__ Q, const float* __restrict__ bias,
                             float* __restrict__ out)
{
    const int K = S_, N = OUTD;
    int b = blockIdx.z;
    const ushort_t* A  = Wt + (int64_t)b * S_ * S_;
    const ushort_t* Bm = PT + (int64_t)b * OUTD * S_;
    const ushort_t* Qb = Q  + (int64_t)b * S_ * OUTD;
    float* Cb = out + (int64_t)b * S_ * OUTD;

    __shared__ __align__(16) ushort_t lds[3 * 24576];

    int t    = threadIdx.x;
    int m0   = blockIdx.y * 256, n0 = blockIdx.x * 128;
    int wave = t >> 6, lane = t & 63;
    int wr   = (wave >> 1) * 64;
    int wc   = (wave & 1) * 64;
    int l15  = lane & 15, quad = lane >> 4;

    f32x4 acc[4][4];
#pragma unroll
    for (int i = 0; i < 4; i++)
#pragma unroll
        for (int j = 0; j < 4; j++) acc[i][j] = (f32x4){0.f, 0.f, 0.f, 0.f};

    int srow = t >> 3;
    int cg   = (t & 7) ^ (srow & 7);
    int scol = cg * 8;

    const ushort_t* gA = A  + (int64_t)(m0 + srow) * K + scol;
    const ushort_t* gB = Bm + (int64_t)(n0 + srow) * K + scol;

    auto stage = [&](int bufi, int k0) {
        ushort_t* Lb = lds + bufi * 24576 + t * 8;
        ld16(gA + k0,                      Lb);
        ld16(gA + (int64_t)64  * K + k0,   Lb + 4096);
        ld16(gA + (int64_t)128 * K + k0,   Lb + 8192);
        ld16(gA + (int64_t)192 * K + k0,   Lb + 12288);
        ld16(gB + k0,                      Lb + 16384);
        ld16(gB + (int64_t)64  * K + k0,   Lb + 20480);
    };

    int aoff[4][2], boff[4][2];
#pragma unroll
    for (int i = 0; i < 4; i++) {
        int R = wr + i * 16 + l15;
#pragma unroll
        for (int h = 0; h < 2; h++) {
            int c = quad + h * 4;
            aoff[i][h] = R * 64 + ((c ^ (R & 7)) << 3);
        }
    }
#pragma unroll
    for (int j = 0; j < 4; j++) {
        int R = wc + j * 16 + l15;
#pragma unroll
        for (int h = 0; h < 2; h++) {
            int c = quad + h * 4;
            boff[j][h] = 16384 + R * 64 + ((c ^ (R & 7)) << 3);
        }
    }

    const int NT = K >> 6;                  // 32
    stage(0, 0);
    stage(1, 64);

    for (int kt = 0; kt < NT; ++kt) {
        if (kt + 1 < NT) {
            asm volatile("s_waitcnt vmcnt(6)" ::: "memory");
        } else {
            asm volatile("s_waitcnt vmcnt(0)" ::: "memory");
        }
        __builtin_amdgcn_s_barrier();
        asm volatile("" ::: "memory");
        __builtin_amdgcn_sched_barrier(0);

        if (kt + 2 < NT) stage((kt + 2) % 3, (kt + 2) * 64);

        const ushort_t* Lb = lds + (kt % 3) * 24576;
#pragma unroll
        for (int h = 0; h < 2; h++) {
            half8 af[4], bf[4];
#pragma unroll
            for (int i = 0; i < 4; i++) af[i] = *(const half8*)(Lb + aoff[i][h]);
#pragma unroll
            for (int j = 0; j < 4; j++) bf[j] = *(const half8*)(Lb + boff[j][h]);
            __builtin_amdgcn_s_setprio(1);
#pragma unroll
            for (int i = 0; i < 4; i++)
#pragma unroll
                for (int j = 0; j < 4; j++)
                    acc[i][j] = __builtin_amdgcn_mfma_f32_16x16x32_f16(af[i], bf[j], acc[i][j], 0, 0, 0);
            __builtin_amdgcn_s_setprio(0);
        }
    }

#pragma unroll
    for (int i = 0; i < 4; i++) {
        int row_base = m0 + wr + i * 16 + quad * 4;
#pragma unroll
        for (int j = 0; j < 4; j++) {
            int col = n0 + wc + j * 16 + l15;
            float bv = bias[col];
#pragma unroll
            for (int r = 0; r < 4; r++) {
                int64_t idx = (int64_t)(row_base + r) * N + col;
                Cb[idx] = acc[i][j][r] + h2f(Qb[idx]) + bv;
            }
        }
    }
}

// ------------------------------- launcher ----------------------------------

extern "C" void kernel_launch(void* const* d_in, const int* in_sizes, int n_in,
                              void* d_out, int out_size, void* d_ws, size_t ws_size,
                              hipStream_t stream)
{
    const float* src  = (const float*)d_in[0];
    const float* tgt  = (const float*)d_in[1];
    const float* W    = (const float*)d_in[2];
    const float* bias = (const float*)d_in[3];

    float* out = (float*)d_out;                           // [4,2048,1024]
    float* Lw  = out + (size_t)B_ * S_ * OUTD;            // [4,2048,2048] logits -> weight

    char*  ws = (char*)d_ws;
    size_t o  = 0;
    auto take = [&](size_t bytes) -> char* {
        char* p = ws + o;
        o += (bytes + 255) & ~(size_t)255;
        return p;
    };
    const size_t ELEMS = (size_t)B_ * S_ * D_;            // 8,388,608
    ushort_t* sh   = (ushort_t*)take(ELEMS * 2);          // src f16
    ushort_t* th   = (ushort_t*)take(ELEMS * 2);          // tgt hi f16
    ushort_t* tl   = (ushort_t*)take(ELEMS * 2);          // tgt lo f16
    ushort_t* wbf  = (ushort_t*)take((size_t)B_ * S_ * S_ * 2);     // weight f16
    ushort_t* wb   = (ushort_t*)take((size_t)OUTD * 2 * D_ * 2);    // W f16 [1024,2048]
    ushort_t* PT   = (ushort_t*)take((size_t)B_ * OUTD * S_ * 2);   // W1@src^T f16 [b,1024,2048]
    ushort_t* Qb   = (ushort_t*)take((size_t)B_ * S_ * OUTD * 2);   // tgt@W2^T f16 [b,2048,1024]
    float*    pm   = (float*)take(16 * (size_t)B_ * S_ * 4);
    float*    ps   = (float*)take(16 * (size_t)B_ * S_ * 4);
    float*    cmax = (float*)take((size_t)B_ * S_ * 4);
    float*    cinv = (float*)take((size_t)B_ * S_ * 4);
    (void)ws_size; (void)in_sizes; (void)n_in; (void)out_size;

    k_split<<<dim3(2048), dim3(256), 0, stream>>>((const float4*)src, (const float4*)tgt,
                                                  (ushort4*)sh, (ushort4*)th, (ushort4*)tl);
    k_wconv<<<dim3(512), dim3(256), 0, stream>>>((const float4*)W, (ushort4*)wb);

    // PT[b][n][s] = sum_d W1[n][d] * src[b][s][d]   (M=1024, N=2048, K=1024)
    k_gemm_nt2<<<dim3(16, 4, 4), dim3(512), 0, stream>>>(
        wb, 2 * D_, 0,
        sh, D_, (int64_t)S_ * D_,
        PT, S_, (int64_t)OUTD * S_, D_);

    // Q[b][t][n] = sum_d tgt[b][t][d] * W2[n][d]    (M=2048, N=1024, K=1024)
    k_gemm_nt2<<<dim3(8, 8, 4), dim3(512), 0, stream>>>(
        th, D_, (int64_t)S_ * D_,
        wb + D_, 2 * D_, 0,
        Qb, OUTD, (int64_t)S_ * OUTD, D_);

    k_gemm_logits<<<dim3(8, 8, 4), dim3(512), 0, stream>>>(th, tl, sh, Lw, pm, ps);

    k_colstats2<<<dim3(32), dim3(256), 0, stream>>>(pm, ps, cmax, cinv);
    k_softmax_norm<<<dim3(2048), dim3(256), 0, stream>>>((float4*)Lw, (const float4*)cmax,
                                                         (const float4*)cinv, (ushort4*)wbf);

    k_gemm_final<<<dim3(8, 8, 4), dim3(512), 0, stream>>>(wbf, PT, Qb, bias, out);
}

// Round 4
// 347.744 us; speedup vs baseline: 1.0115x; 1.0115x over previous
//
#include <hip/hip_runtime.h>
#include <stdint.h>

// ---------------------------------------------------------------------------
// Attention_18116172054662 on MI355X (gfx950)
//   L = tgt @ src^T  (2-term split-f16: (tgt_hi + tgt_lo) @ src_f16)
//   weight = softmax(L, axis=tgt)   -> second output (f32, in place in d_out)
//   out = weight @ PT^T + Q + b  where  PT = W1 @ src^T,  Q = tgt @ W2^T
// R7: XOR chunk swizzle (slot = chunk ^ (row&7)) kills 128B-row bank wrap.
// R8: 256x256 / 8-wave / dbuf-prefetch template (conflicts 6.3M -> 0).
// R9: ported to PT/Q/final (256x128, BK=64). 358 -> 348.
// R10: counted vmcnt(6), 3 LDS bufs, 2-deep prefetch. NEUTRAL on the
//     1-phase structure (matches m218 regime gate: counted pays only
//     with phase interleave).
// R11: logits -> genuine 8-phase interleave (T3): 4 phases per K-step,
//     each {4-8 ds_reads + 2 staging loads, s_barrier, 16 MFMA w/ setprio,
//     s_barrier}. Wave layout 2Mx4N (128x64/wave, acc[8][4]); each A-frag
//     lives exactly one phase; bf[4] lives one K-step. Breaks the
//     96-read-per-CU post-barrier burst (every wave's MFMA waited the
//     whole burst) into 4 overlapped 48-read phases.
// ---------------------------------------------------------------------------

#define B_   4
#define S_   2048
#define D_   1024
#define OUTD 1024

typedef unsigned short ushort_t;
typedef _Float16 half8 __attribute__((ext_vector_type(8)));
typedef float    f32x4 __attribute__((ext_vector_type(4)));

__device__ __forceinline__ ushort_t f2h(float f) {
    union { _Float16 h; ushort_t u; } v;
    v.h = (_Float16)f;                    // RNE
    return v.u;
}
__device__ __forceinline__ float h2f(ushort_t u) {
    union { _Float16 h; ushort_t u; } v;
    v.u = u;
    return (float)v.h;
}

// async global->LDS, 16B per lane; LDS dest = wave-uniform base + lane*16
__device__ __forceinline__ void ld16(const ushort_t* g, ushort_t* l) {
    __builtin_amdgcn_global_load_lds(
        (const __attribute__((address_space(1))) void*)g,
        (__attribute__((address_space(3))) void*)l, 16, 0, 0);
}

// --------------------------- elementwise prep ------------------------------

// src -> f16; tgt -> f16 hi + f16 lo
__global__ void k_split(const float4* __restrict__ src, const float4* __restrict__ tgt,
                        ushort4* __restrict__ sh,
                        ushort4* __restrict__ th, ushort4* __restrict__ tl)
{
    const int64_t n4 = (int64_t)B_ * S_ * D_ / 4;
    for (int64_t i = (int64_t)blockIdx.x * blockDim.x + threadIdx.x; i < n4;
         i += (int64_t)gridDim.x * blockDim.x) {
        float4 s = src[i];
        sh[i] = (ushort4){f2h(s.x), f2h(s.y), f2h(s.z), f2h(s.w)};
        float4 tv = tgt[i];
        ushort4 ht = {f2h(tv.x), f2h(tv.y), f2h(tv.z), f2h(tv.w)};
        th[i] = ht;
        tl[i] = (ushort4){f2h(tv.x - h2f(ht.x)), f2h(tv.y - h2f(ht.y)),
                          f2h(tv.z - h2f(ht.z)), f2h(tv.w - h2f(ht.w))};
    }
}

__global__ void k_wconv(const float4* __restrict__ W, ushort4* __restrict__ wb)
{
    const int64_t n4 = (int64_t)OUTD * 2 * D_ / 4;
    for (int64_t i = (int64_t)blockIdx.x * blockDim.x + threadIdx.x; i < n4;
         i += (int64_t)gridDim.x * blockDim.x) {
        float4 w = W[i];
        wb[i] = (ushort4){f2h(w.x), f2h(w.y), f2h(w.z), f2h(w.w)};
    }
}

// ------------------------------- GEMM 1 ------------------------------------
// L[b] = tgt[b] @ src[b]^T, 2-term f16 split:  Ah*B + Al*B
// 256x256 tile, BK=32, 8 waves 2Mx4N of 128x64, 16x16x32 f16 MFMA.
// Triple-buffered LDS, counted vmcnt(6), prefetch 2 deep, 4-phase interleave
// per K-step: phase p = {reads (4 A + [4 B in p0]) + 2 staging loads,
// s_barrier, 16 MFMA (setprio 1), s_barrier}.
// LDS layout per 256x32 tile: paired rows -> [128][64] f16, 128B lines,
//   chunk_g = (r&1)*4 + (k>>3); slot = chunk_g ^ ((r>>1)&7); 16B chunks.
// Epilogue: per-block (256-row chunk) column max/sumexp -> pm/ps (8 chunks).
__launch_bounds__(512, 2)
__global__ void k_gemm_logits(const ushort_t* __restrict__ Ah, const ushort_t* __restrict__ Al,
                              const ushort_t* __restrict__ Bs,
                              float* __restrict__ C,
                              float* __restrict__ pm, float* __restrict__ ps)
{
    const int M = S_, N = S_, K = D_;
    int b = blockIdx.z;
    Ah += (int64_t)b * M * K;  Al += (int64_t)b * M * K;
    Bs += (int64_t)b * N * K;
    C  += (int64_t)b * M * N;

    // 3 bufs x { Ah 16KB | Al 16KB | B 16KB }  (ushort units; 144 KiB total)
    __shared__ __align__(16) ushort_t lds[3 * 24576];
    __shared__ float red_m[2][256], red_s[2][256];

    int t    = threadIdx.x;                 // 0..511
    int m0   = blockIdx.y * 256, n0 = blockIdx.x * 256;
    int wave = t >> 6, lane = t & 63;
    int wr   = (wave >> 2) * 128;           // 0,128
    int wc   = (wave & 3) * 64;             // 0,64,128,192
    int l15  = lane & 15, quad = lane >> 4;

    f32x4 acc[8][4];
#pragma unroll
    for (int i = 0; i < 8; i++)
#pragma unroll
        for (int j = 0; j < 4; j++) acc[i][j] = (f32x4){0.f, 0.f, 0.f, 0.f};

    // ---- staging map: thread t writes LDS bytes [t*16, t*16+16) of each
    //      8KB pass (pass covers 64 paired-rows = 128 global rows).
    //      Invert the swizzle on the GLOBAL side; LDS dest stays linear.
    int pr   = t >> 3;                      // paired-row 0..63 within pass
    int slot = t & 7;
    int cg   = slot ^ (pr & 7);
    int srow = pr * 2 + (cg >> 2);          // 0..127 (+128 for pass 1)
    int scol = (cg & 3) * 8;                // f16 col within BK=32

    const ushort_t* gAh = Ah + (int64_t)(m0 + srow) * K + scol;
    const ushort_t* gAl = Al + (int64_t)(m0 + srow) * K + scol;
    const ushort_t* gB  = Bs + (int64_t)(n0 + srow) * K + scol;
    const int64_t rstep = (int64_t)128 * K;     // pass-1 global row offset

    auto stage_all = [&](int bufi, int kofs) {  // prologue only
        ushort_t* Lb = lds + bufi * 24576 + t * 8;
        ld16(gAh + kofs,         Lb);
        ld16(gAh + rstep + kofs, Lb + 4096);
        ld16(gAl + kofs,         Lb + 8192);
        ld16(gAl + rstep + kofs, Lb + 12288);
        ld16(gB  + kofs,         Lb + 16384);
        ld16(gB  + rstep + kofs, Lb + 20480);
    };

    // ---- ds_read offsets (ushort units within one 16KB tile)
    int aoff[8], boff[4];
#pragma unroll
    for (int i = 0; i < 8; i++) {
        int R = wr + i * 16 + l15;
        int p = R >> 1, c = ((R & 1) << 2) + quad;
        aoff[i] = p * 64 + ((c ^ (p & 7)) << 3);
    }
#pragma unroll
    for (int j = 0; j < 4; j++) {
        int R = wc + j * 16 + l15;
        int p = R >> 1, c = ((R & 1) << 2) + quad;
        boff[j] = p * 64 + ((c ^ (p & 7)) << 3);
    }

    const int NT = 32;
    stage_all(0, 0);                        // prologue: tiles 0 and 1 in flight
    stage_all(1, 32);

    for (int kt = 0; kt < NT; ++kt) {
        const ushort_t* Lb = lds + (kt % 3) * 24576;
        ushort_t* Ld = lds + ((kt + 2) % 3) * 24576 + t * 8;
        const int nofs = (kt + 2) * 32;
        const bool pre = (kt + 2) < NT;

        // own oldest 6 loads (tile kt) done; barrier makes it collective
        if (kt + 1 < NT) {
            asm volatile("s_waitcnt vmcnt(6)" ::: "memory");
        } else {
            asm volatile("s_waitcnt vmcnt(0)" ::: "memory");
        }
        __builtin_amdgcn_s_barrier();
        asm volatile("" ::: "memory");
        __builtin_amdgcn_sched_barrier(0);

        half8 av[4], bf[4];

        // ---- phase 0: bf + ah(rh0); stage Ah(kt+2) ----
#pragma unroll
        for (int j = 0; j < 4; j++) bf[j] = *(const half8*)(Lb + 16384 + boff[j]);
#pragma unroll
        for (int i = 0; i < 4; i++) av[i] = *(const half8*)(Lb + aoff[i]);
        if (pre) { ld16(gAh + nofs, Ld);  ld16(gAh + rstep + nofs, Ld + 4096); }
        __builtin_amdgcn_s_barrier();
        __builtin_amdgcn_s_setprio(1);
#pragma unroll
        for (int i = 0; i < 4; i++)
#pragma unroll
            for (int j = 0; j < 4; j++)
                acc[i][j] = __builtin_amdgcn_mfma_f32_16x16x32_f16(av[i], bf[j], acc[i][j], 0, 0, 0);
        __builtin_amdgcn_s_setprio(0);
        __builtin_amdgcn_s_barrier();

        // ---- phase 1: al(rh0); stage Al(kt+2) ----
#pragma unroll
        for (int i = 0; i < 4; i++) av[i] = *(const half8*)(Lb + 8192 + aoff[i]);
        if (pre) { ld16(gAl + nofs, Ld + 8192);  ld16(gAl + rstep + nofs, Ld + 12288); }
        __builtin_amdgcn_s_barrier();
        __builtin_amdgcn_s_setprio(1);
#pragma unroll
        for (int i = 0; i < 4; i++)
#pragma unroll
            for (int j = 0; j < 4; j++)
                acc[i][j] = __builtin_amdgcn_mfma_f32_16x16x32_f16(av[i], bf[j], acc[i][j], 0, 0, 0);
        __builtin_amdgcn_s_setprio(0);
        __builtin_amdgcn_s_barrier();

        // ---- phase 2: ah(rh1); stage B(kt+2) ----
#pragma unroll
        for (int i = 0; i < 4; i++) av[i] = *(const half8*)(Lb + aoff[4 + i]);
        if (pre) { ld16(gB + nofs, Ld + 16384);  ld16(gB + rstep + nofs, Ld + 20480); }
        __builtin_amdgcn_s_barrier();
        __builtin_amdgcn_s_setprio(1);
#pragma unroll
        for (int i = 0; i < 4; i++)
#pragma unroll
            for (int j = 0; j < 4; j++)
                acc[4 + i][j] = __builtin_amdgcn_mfma_f32_16x16x32_f16(av[i], bf[j], acc[4 + i][j], 0, 0, 0);
        __builtin_amdgcn_s_setprio(0);
        __builtin_amdgcn_s_barrier();

        // ---- phase 3: al(rh1) ----  (tail barrier elided: next head has one)
#pragma unroll
        for (int i = 0; i < 4; i++) av[i] = *(const half8*)(Lb + 8192 + aoff[4 + i]);
        __builtin_amdgcn_s_barrier();
        __builtin_amdgcn_s_setprio(1);
#pragma unroll
        for (int i = 0; i < 4; i++)
#pragma unroll
            for (int j = 0; j < 4; j++)
                acc[4 + i][j] = __builtin_amdgcn_mfma_f32_16x16x32_f16(av[i], bf[j], acc[4 + i][j], 0, 0, 0);
        __builtin_amdgcn_s_setprio(0);
    }

    // C store (f32, coalesced per 16 lanes)
#pragma unroll
    for (int i = 0; i < 8; i++) {
        int row_base = m0 + wr + i * 16 + quad * 4;
#pragma unroll
        for (int j = 0; j < 4; j++) {
            int col = n0 + wc + j * 16 + l15;
#pragma unroll
            for (int r = 0; r < 4; r++)
                C[(int64_t)(row_base + r) * N + col] = acc[i][j][r];
        }
    }

    // fused partial column stats (max & sumexp over this block's 256 rows)
    int wrow = wave >> 2;                   // row-half of the block
#pragma unroll
    for (int j = 0; j < 4; j++) {
        float m = -3.0e38f;
#pragma unroll
        for (int i = 0; i < 8; i++)
#pragma unroll
            for (int r = 0; r < 4; r++) m = fmaxf(m, acc[i][j][r]);
        float s = 0.f;
#pragma unroll
        for (int i = 0; i < 8; i++)
#pragma unroll
            for (int r = 0; r < 4; r++) s += __expf(acc[i][j][r] - m);
#pragma unroll
        for (int d = 16; d <= 32; d <<= 1) {
            float m2 = __shfl_xor(m, d, 64);
            float s2 = __shfl_xor(s, d, 64);
            float nm = fmaxf(m, m2);
            s = s * __expf(m - nm) + s2 * __expf(m2 - nm);
            m = nm;
        }
        if (lane < 16) {
            red_m[wrow][wc + j * 16 + l15] = m;
            red_s[wrow][wc + j * 16 + l15] = s;
        }
    }
    __syncthreads();
    if (t < 256) {
        float ma = red_m[0][t], mb = red_m[1][t];
        float sa = red_s[0][t], sb = red_s[1][t];
        float m = fmaxf(ma, mb);
        float s = sa * __expf(ma - m) + sb * __expf(mb - m);
        int idx = blockIdx.y * (B_ * S_) + b * S_ + n0 + t;
        pm[idx] = m;
        ps[idx] = s;
    }
}

// --------------------------- column softmax --------------------------------

__global__ void k_colstats2(const float* __restrict__ pm, const float* __restrict__ ps,
                            float* __restrict__ cmax, float* __restrict__ cinv)
{
    int i = blockIdx.x * 256 + threadIdx.x;   // 8192
    float m = -3.0e38f;
#pragma unroll
    for (int c = 0; c < 8; c++) m = fmaxf(m, pm[c * (B_ * S_) + i]);
    float sum = 0.f;
#pragma unroll
    for (int c = 0; c < 8; c++) sum += ps[c * (B_ * S_) + i] * __expf(pm[c * (B_ * S_) + i] - m);
    cmax[i] = m;
    cinv[i] = 1.0f / sum;
}

// weight = exp(L - cmax)/csum, in place; also emit f16 copy for the final GEMM
__global__ void k_softmax_norm(float4* __restrict__ L, const float4* __restrict__ cmax4,
                               const float4* __restrict__ cinv4, ushort4* __restrict__ wbf)
{
    const int64_t n4 = (int64_t)B_ * S_ * S_ / 4;
    for (int64_t i = (int64_t)blockIdx.x * blockDim.x + threadIdx.x; i < n4;
         i += (int64_t)gridDim.x * blockDim.x) {
        int b  = (int)(i >> 20);
        int c4 = (int)(i & 511);
        float4 x  = L[i];
        float4 cm = cmax4[b * 512 + c4];
        float4 ci = cinv4[b * 512 + c4];
        float4 w;
        w.x = __expf(x.x - cm.x) * ci.x;
        w.y = __expf(x.y - cm.y) * ci.y;
        w.z = __expf(x.z - cm.z) * ci.z;
        w.w = __expf(x.w - cm.w) * ci.w;
        L[i] = w;
        wbf[i] = (ushort4){f2h(w.x), f2h(w.y), f2h(w.z), f2h(w.w)};
    }
}

// ------------------ NT f16 GEMM, R10 structure ------------------------------
// C[m][n] = sum_k A[m][k]*B[n][k].  256x128 tile, BK=64, 8 waves 4x2 of
// 64x64, 16x16x32 f16 MFMA.  Triple-buffered LDS (144KB), counted vmcnt(6)
// + raw s_barrier per K-tile, prefetch 2 tiles deep, XOR chunk swizzle
// (slot = chunk ^ (row&7)) on GLOBAL side for staging / addresses for reads.
// LDS per tile: A 256x64 (32KB) @0, B 128x64 (16KB) @16384 (ushort units).
__launch_bounds__(512, 2)
__global__ void k_gemm_nt2(const ushort_t* __restrict__ A, int lda, int64_t bsA,
                           const ushort_t* __restrict__ Bm, int ldb, int64_t bsB,
                           ushort_t* __restrict__ C, int ldc, int64_t bsC, int K)
{
    int b = blockIdx.z;
    A  += (int64_t)b * bsA;
    Bm += (int64_t)b * bsB;
    C  += (int64_t)b * bsC;

    __shared__ __align__(16) ushort_t lds[3 * 24576];

    int t    = threadIdx.x;                 // 0..511
    int m0   = blockIdx.y * 256, n0 = blockIdx.x * 128;
    int wave = t >> 6, lane = t & 63;
    int wr   = (wave >> 1) * 64;            // 0,64,128,192
    int wc   = (wave & 1) * 64;             // 0,64
    int l15  = lane & 15, quad = lane >> 4;

    f32x4 acc[4][4];
#pragma unroll
    for (int i = 0; i < 4; i++)
#pragma unroll
        for (int j = 0; j < 4; j++) acc[i][j] = (f32x4){0.f, 0.f, 0.f, 0.f};

    // staging: thread t covers (row = srow + 64*pass, 16B chunk cg) where the
    // swizzle is inverted on the global side; LDS dest linear at t*16B/pass.
    int srow = t >> 3;                      // 0..63
    int cg   = (t & 7) ^ (srow & 7);
    int scol = cg * 8;

    const ushort_t* gA = A  + (int64_t)(m0 + srow) * lda + scol;
    const ushort_t* gB = Bm + (int64_t)(n0 + srow) * ldb + scol;

    auto stage = [&](int bufi, int k0) {
        ushort_t* Lb = lds + bufi * 24576 + t * 8;
        ld16(gA + k0,                        Lb);
        ld16(gA + (int64_t)64  * lda + k0,   Lb + 4096);
        ld16(gA + (int64_t)128 * lda + k0,   Lb + 8192);
        ld16(gA + (int64_t)192 * lda + k0,   Lb + 12288);
        ld16(gB + k0,                        Lb + 16384);
        ld16(gB + (int64_t)64  * ldb + k0,   Lb + 20480);
    };

    // read offsets (ushort units), h = K-half (ks = h*32)
    int aoff[4][2], boff[4][2];
#pragma unroll
    for (int i = 0; i < 4; i++) {
        int R = wr + i * 16 + l15;
#pragma unroll
        for (int h = 0; h < 2; h++) {
            int c = quad + h * 4;
            aoff[i][h] = R * 64 + ((c ^ (R & 7)) << 3);
        }
    }
#pragma unroll
    for (int j = 0; j < 4; j++) {
        int R = wc + j * 16 + l15;
#pragma unroll
        for (int h = 0; h < 2; h++) {
            int c = quad + h * 4;
            boff[j][h] = 16384 + R * 64 + ((c ^ (R & 7)) << 3);
        }
    }

    const int NT = K >> 6;
    stage(0, 0);
    stage(1, 64);

    for (int kt = 0; kt < NT; ++kt) {
        if (kt + 1 < NT) {
            asm volatile("s_waitcnt vmcnt(6)" ::: "memory");
        } else {
            asm volatile("s_waitcnt vmcnt(0)" ::: "memory");
        }
        __builtin_amdgcn_s_barrier();
        asm volatile("" ::: "memory");
        __builtin_amdgcn_sched_barrier(0);

        if (kt + 2 < NT) stage((kt + 2) % 3, (kt + 2) * 64);

        const ushort_t* Lb = lds + (kt % 3) * 24576;
#pragma unroll
        for (int h = 0; h < 2; h++) {
            half8 af[4], bf[4];
#pragma unroll
            for (int i = 0; i < 4; i++) af[i] = *(const half8*)(Lb + aoff[i][h]);
#pragma unroll
            for (int j = 0; j < 4; j++) bf[j] = *(const half8*)(Lb + boff[j][h]);
            __builtin_amdgcn_s_setprio(1);
#pragma unroll
            for (int i = 0; i < 4; i++)
#pragma unroll
                for (int j = 0; j < 4; j++)
                    acc[i][j] = __builtin_amdgcn_mfma_f32_16x16x32_f16(af[i], bf[j], acc[i][j], 0, 0, 0);
            __builtin_amdgcn_s_setprio(0);
        }
    }

#pragma unroll
    for (int i = 0; i < 4; i++) {
        int row_base = m0 + wr + i * 16 + quad * 4;
#pragma unroll
        for (int j = 0; j < 4; j++) {
            int col = n0 + wc + j * 16 + l15;
#pragma unroll
            for (int r = 0; r < 4; r++)
                C[(int64_t)(row_base + r) * ldc + col] = f2h(acc[i][j][r]);
        }
    }
}

// --------------------------- final GEMM (R10) -------------------------------
// out[b][t][n] = sum_s weight_f16[b][t][s]*PT[b][n][s] + Q[b][t][n] + bias[n]
// Same 256x128 / BK=64 / 8-wave 3-buf counted structure; f32 out + Q + bias.
__launch_bounds__(512, 2)
__global__ void k_gemm_final(const ushort_t* __restrict__ Wt, const ushort_t* __restrict__ PT,
                             const ushort_t* __restrict__ Q, const float* __restrict__ bias,
                             float* __restrict__ out)
{
    const int K = S_, N = OUTD;
    int b = blockIdx.z;
    const ushort_t* A  = Wt + (int64_t)b * S_ * S_;
    const ushort_t* Bm = PT + (int64_t)b * OUTD * S_;
    const ushort_t* Qb = Q  + (int64_t)b * S_ * OUTD;
    float* Cb = out + (int64_t)b * S_ * OUTD;

    __shared__ __align__(16) ushort_t lds[3 * 24576];

    int t    = threadIdx.x;
    int m0   = blockIdx.y * 256, n0 = blockIdx.x * 128;
    int wave = t >> 6, lane = t & 63;
    int wr   = (wave >> 1) * 64;
    int wc   = (wave & 1) * 64;
    int l15  = lane & 15, quad = lane >> 4;

    f32x4 acc[4][4];
#pragma unroll
    for (int i = 0; i < 4; i++)
#pragma unroll
        for (int j = 0; j < 4; j++) acc[i][j] = (f32x4){0.f, 0.f, 0.f, 0.f};

    int srow = t >> 3;
    int cg   = (t & 7) ^ (srow & 7);
    int scol = cg * 8;

    const ushort_t* gA = A  + (int64_t)(m0 + srow) * K + scol;
    const ushort_t* gB = Bm + (int64_t)(n0 + srow) * K + scol;

    auto stage = [&](int bufi, int k0) {
        ushort_t* Lb = lds + bufi * 24576 + t * 8;
        ld16(gA + k0,                      Lb);
        ld16(gA + (int64_t)64  * K + k0,   Lb + 4096);
        ld16(gA + (int64_t)128 * K + k0,   Lb + 8192);
        ld16(gA + (int64_t)192 * K + k0,   Lb + 12288);
        ld16(gB + k0,                      Lb + 16384);
        ld16(gB + (int64_t)64  * K + k0,   Lb + 20480);
    };

    int aoff[4][2], boff[4][2];
#pragma unroll
    for (int i = 0; i < 4; i++) {
        int R = wr + i * 16 + l15;
#pragma unroll
        for (int h = 0; h < 2; h++) {
            int c = quad + h * 4;
            aoff[i][h] = R * 64 + ((c ^ (R & 7)) << 3);
        }
    }
#pragma unroll
    for (int j = 0; j < 4; j++) {
        int R = wc + j * 16 + l15;
#pragma unroll
        for (int h = 0; h < 2; h++) {
            int c = quad + h * 4;
            boff[j][h] = 16384 + R * 64 + ((c ^ (R & 7)) << 3);
        }
    }

    const int NT = K >> 6;                  // 32
    stage(0, 0);
    stage(1, 64);

    for (int kt = 0; kt < NT; ++kt) {
        if (kt + 1 < NT) {
            asm volatile("s_waitcnt vmcnt(6)" ::: "memory");
        } else {
            asm volatile("s_waitcnt vmcnt(0)" ::: "memory");
        }
        __builtin_amdgcn_s_barrier();
        asm volatile("" ::: "memory");
        __builtin_amdgcn_sched_barrier(0);

        if (kt + 2 < NT) stage((kt + 2) % 3, (kt + 2) * 64);

        const ushort_t* Lb = lds + (kt % 3) * 24576;
#pragma unroll
        for (int h = 0; h < 2; h++) {
            half8 af[4], bf[4];
#pragma unroll
            for (int i = 0; i < 4; i++) af[i] = *(const half8*)(Lb + aoff[i][h]);
#pragma unroll
            for (int j = 0; j < 4; j++) bf[j] = *(const half8*)(Lb + boff[j][h]);
            __builtin_amdgcn_s_setprio(1);
#pragma unroll
            for (int i = 0; i < 4; i++)
#pragma unroll
                for (int j = 0; j < 4; j++)
                    acc[i][j] = __builtin_amdgcn_mfma_f32_16x16x32_f16(af[i], bf[j], acc[i][j], 0, 0, 0);
            __builtin_amdgcn_s_setprio(0);
        }
    }

#pragma unroll
    for (int i = 0; i < 4; i++) {
        int row_base = m0 + wr + i * 16 + quad * 4;
#pragma unroll
        for (int j = 0; j < 4; j++) {
            int col = n0 + wc + j * 16 + l15;
            float bv = bias[col];
#pragma unroll
            for (int r = 0; r < 4; r++) {
                int64_t idx = (int64_t)(row_base + r) * N + col;
                Cb[idx] = acc[i][j][r] + h2f(Qb[idx]) + bv;
            }
        }
    }
}

// ------------------------------- launcher ----------------------------------

extern "C" void kernel_launch(void* const* d_in, const int* in_sizes, int n_in,
                              void* d_out, int out_size, void* d_ws, size_t ws_size,
                              hipStream_t stream)
{
    const float* src  = (const float*)d_in[0];
    const float* tgt  = (const float*)d_in[1];
    const float* W    = (const float*)d_in[2];
    const float* bias = (const float*)d_in[3];

    float* out = (float*)d_out;                           // [4,2048,1024]
    float* Lw  = out + (size_t)B_ * S_ * OUTD;            // [4,2048,2048] logits -> weight

    char*  ws = (char*)d_ws;
    size_t o  = 0;
    auto take = [&](size_t bytes) -> char* {
        char* p = ws + o;
        o += (bytes + 255) & ~(size_t)255;
        return p;
    };
    const size_t ELEMS = (size_t)B_ * S_ * D_;            // 8,388,608
    ushort_t* sh   = (ushort_t*)take(ELEMS * 2);          // src f16
    ushort_t* th   = (ushort_t*)take(ELEMS * 2);          // tgt hi f16
    ushort_t* tl   = (ushort_t*)take(ELEMS * 2);          // tgt lo f16
    ushort_t* wbf  = (ushort_t*)take((size_t)B_ * S_ * S_ * 2);     // weight f16
    ushort_t* wb   = (ushort_t*)take((size_t)OUTD * 2 * D_ * 2);    // W f16 [1024,2048]
    ushort_t* PT   = (ushort_t*)take((size_t)B_ * OUTD * S_ * 2);   // W1@src^T f16 [b,1024,2048]
    ushort_t* Qb   = (ushort_t*)take((size_t)B_ * S_ * OUTD * 2);   // tgt@W2^T f16 [b,2048,1024]
    float*    pm   = (float*)take(16 * (size_t)B_ * S_ * 4);
    float*    ps   = (float*)take(16 * (size_t)B_ * S_ * 4);
    float*    cmax = (float*)take((size_t)B_ * S_ * 4);
    float*    cinv = (float*)take((size_t)B_ * S_ * 4);
    (void)ws_size; (void)in_sizes; (void)n_in; (void)out_size;

    k_split<<<dim3(2048), dim3(256), 0, stream>>>((const float4*)src, (const float4*)tgt,
                                                  (ushort4*)sh, (ushort4*)th, (ushort4*)tl);
    k_wconv<<<dim3(512), dim3(256), 0, stream>>>((const float4*)W, (ushort4*)wb);

    // PT[b][n][s] = sum_d W1[n][d] * src[b][s][d]   (M=1024, N=2048, K=1024)
    k_gemm_nt2<<<dim3(16, 4, 4), dim3(512), 0, stream>>>(
        wb, 2 * D_, 0,
        sh, D_, (int64_t)S_ * D_,
        PT, S_, (int64_t)OUTD * S_, D_);

    // Q[b][t][n] = sum_d tgt[b][t][d] * W2[n][d]    (M=2048, N=1024, K=1024)
    k_gemm_nt2<<<dim3(8, 8, 4), dim3(512), 0, stream>>>(
        th, D_, (int64_t)S_ * D_,
        wb + D_, 2 * D_, 0,
        Qb, OUTD, (int64_t)S_ * OUTD, D_);

    k_gemm_logits<<<dim3(8, 8, 4), dim3(512), 0, stream>>>(th, tl, sh, Lw, pm, ps);

    k_colstats2<<<dim3(32), dim3(256), 0, stream>>>(pm, ps, cmax, cinv);
    k_softmax_norm<<<dim3(2048), dim3(256), 0, stream>>>((float4*)Lw, (const float4*)cmax,
                                                         (const float4*)cinv, (ushort4*)wbf);

    k_gemm_final<<<dim3(8, 8, 4), dim3(512), 0, stream>>>(wbf, PT, Qb, bias, out);
}

// Round 5
// 339.580 us; speedup vs baseline: 1.0358x; 1.0240x over previous
//
#include <hip/hip_runtime.h>
#include <stdint.h>

// ---------------------------------------------------------------------------
// Attention_18116172054662 on MI355X (gfx950)
//   L = tgt @ src^T  (2-term split-f16: (tgt_hi + tgt_lo) @ src_f16)
//   weight = softmax(L, axis=tgt)   -> second output (f32, in place in d_out)
//   out = weight @ PT^T + Q + b  where  PT = W1 @ src^T,  Q = tgt @ W2^T
// R7: XOR chunk swizzle (slot = chunk ^ (row&7)) kills 128B-row bank wrap.
// R8: 256x256 / 8-wave / dbuf-prefetch template (conflicts 6.3M -> 0).
// R9: ported to PT/Q/final (256x128, BK=64). 358 -> 348.
// R10: counted vmcnt(6), 3 LDS bufs, 2-deep prefetch. NEUTRAL on 1-phase
//     structure (m218 regime gate confirmed).
// R11: logits 4-phase interleave: 86 -> 77 us, MfmaUtil 32 -> 37%.
// R12: apply the proven phase-interleave to nt2/final (2 phases per BK=64
//     K-tile: {8 ds_reads + 3 staging, bar, 16 MFMA, bar}); merge the two
//     nt2 calls into ONE 512-block launch (tails overlap, -1 dispatch);
//     fuse k_wconv into k_split (-1 dispatch). 8 -> 6 kernels.
// ---------------------------------------------------------------------------

#define B_   4
#define S_   2048
#define D_   1024
#define OUTD 1024

typedef unsigned short ushort_t;
typedef _Float16 half8 __attribute__((ext_vector_type(8)));
typedef float    f32x4 __attribute__((ext_vector_type(4)));

__device__ __forceinline__ ushort_t f2h(float f) {
    union { _Float16 h; ushort_t u; } v;
    v.h = (_Float16)f;                    // RNE
    return v.u;
}
__device__ __forceinline__ float h2f(ushort_t u) {
    union { _Float16 h; ushort_t u; } v;
    v.u = u;
    return (float)v.h;
}

// async global->LDS, 16B per lane; LDS dest = wave-uniform base + lane*16
__device__ __forceinline__ void ld16(const ushort_t* g, ushort_t* l) {
    __builtin_amdgcn_global_load_lds(
        (const __attribute__((address_space(1))) void*)g,
        (__attribute__((address_space(3))) void*)l, 16, 0, 0);
}

// --------------------------- elementwise prep ------------------------------

// src -> f16; tgt -> f16 hi + f16 lo; W -> f16 (fused, R12)
__global__ void k_split(const float4* __restrict__ src, const float4* __restrict__ tgt,
                        const float4* __restrict__ W,
                        ushort4* __restrict__ sh,
                        ushort4* __restrict__ th, ushort4* __restrict__ tl,
                        ushort4* __restrict__ wb)
{
    const int64_t n4 = (int64_t)B_ * S_ * D_ / 4;         // 2,097,152
    const int64_t w4 = (int64_t)OUTD * 2 * D_ / 4;        //   524,288
    for (int64_t i = (int64_t)blockIdx.x * blockDim.x + threadIdx.x; i < n4 + w4;
         i += (int64_t)gridDim.x * blockDim.x) {
        if (i < n4) {
            float4 s = src[i];
            sh[i] = (ushort4){f2h(s.x), f2h(s.y), f2h(s.z), f2h(s.w)};
            float4 tv = tgt[i];
            ushort4 ht = {f2h(tv.x), f2h(tv.y), f2h(tv.z), f2h(tv.w)};
            th[i] = ht;
            tl[i] = (ushort4){f2h(tv.x - h2f(ht.x)), f2h(tv.y - h2f(ht.y)),
                              f2h(tv.z - h2f(ht.z)), f2h(tv.w - h2f(ht.w))};
        } else {
            int64_t j = i - n4;
            float4 w = W[j];
            wb[j] = (ushort4){f2h(w.x), f2h(w.y), f2h(w.z), f2h(w.w)};
        }
    }
}

// ------------------------------- GEMM 1 ------------------------------------
// L[b] = tgt[b] @ src[b]^T, 2-term f16 split:  Ah*B + Al*B
// 256x256 tile, BK=32, 8 waves 2Mx4N of 128x64, 16x16x32 f16 MFMA.
// Triple-buffered LDS, counted vmcnt(6), prefetch 2 deep, 4-phase interleave
// per K-step (R11).  Epilogue: per-block column max/sumexp -> pm/ps.
__launch_bounds__(512, 2)
__global__ void k_gemm_logits(const ushort_t* __restrict__ Ah, const ushort_t* __restrict__ Al,
                              const ushort_t* __restrict__ Bs,
                              float* __restrict__ C,
                              float* __restrict__ pm, float* __restrict__ ps)
{
    const int M = S_, N = S_, K = D_;
    int b = blockIdx.z;
    Ah += (int64_t)b * M * K;  Al += (int64_t)b * M * K;
    Bs += (int64_t)b * N * K;
    C  += (int64_t)b * M * N;

    // 3 bufs x { Ah 16KB | Al 16KB | B 16KB }  (ushort units; 144 KiB total)
    __shared__ __align__(16) ushort_t lds[3 * 24576];
    __shared__ float red_m[2][256], red_s[2][256];

    int t    = threadIdx.x;                 // 0..511
    int m0   = blockIdx.y * 256, n0 = blockIdx.x * 256;
    int wave = t >> 6, lane = t & 63;
    int wr   = (wave >> 2) * 128;           // 0,128
    int wc   = (wave & 3) * 64;             // 0,64,128,192
    int l15  = lane & 15, quad = lane >> 4;

    f32x4 acc[8][4];
#pragma unroll
    for (int i = 0; i < 8; i++)
#pragma unroll
        for (int j = 0; j < 4; j++) acc[i][j] = (f32x4){0.f, 0.f, 0.f, 0.f};

    int pr   = t >> 3;                      // paired-row 0..63 within pass
    int slot = t & 7;
    int cg   = slot ^ (pr & 7);
    int srow = pr * 2 + (cg >> 2);          // 0..127 (+128 for pass 1)
    int scol = (cg & 3) * 8;                // f16 col within BK=32

    const ushort_t* gAh = Ah + (int64_t)(m0 + srow) * K + scol;
    const ushort_t* gAl = Al + (int64_t)(m0 + srow) * K + scol;
    const ushort_t* gB  = Bs + (int64_t)(n0 + srow) * K + scol;
    const int64_t rstep = (int64_t)128 * K;     // pass-1 global row offset

    auto stage_all = [&](int bufi, int kofs) {  // prologue only
        ushort_t* Lb = lds + bufi * 24576 + t * 8;
        ld16(gAh + kofs,         Lb);
        ld16(gAh + rstep + kofs, Lb + 4096);
        ld16(gAl + kofs,         Lb + 8192);
        ld16(gAl + rstep + kofs, Lb + 12288);
        ld16(gB  + kofs,         Lb + 16384);
        ld16(gB  + rstep + kofs, Lb + 20480);
    };

    int aoff[8], boff[4];
#pragma unroll
    for (int i = 0; i < 8; i++) {
        int R = wr + i * 16 + l15;
        int p = R >> 1, c = ((R & 1) << 2) + quad;
        aoff[i] = p * 64 + ((c ^ (p & 7)) << 3);
    }
#pragma unroll
    for (int j = 0; j < 4; j++) {
        int R = wc + j * 16 + l15;
        int p = R >> 1, c = ((R & 1) << 2) + quad;
        boff[j] = p * 64 + ((c ^ (p & 7)) << 3);
    }

    const int NT = 32;
    stage_all(0, 0);                        // prologue: tiles 0 and 1 in flight
    stage_all(1, 32);

    for (int kt = 0; kt < NT; ++kt) {
        const ushort_t* Lb = lds + (kt % 3) * 24576;
        ushort_t* Ld = lds + ((kt + 2) % 3) * 24576 + t * 8;
        const int nofs = (kt + 2) * 32;
        const bool pre = (kt + 2) < NT;

        if (kt + 1 < NT) {
            asm volatile("s_waitcnt vmcnt(6)" ::: "memory");
        } else {
            asm volatile("s_waitcnt vmcnt(0)" ::: "memory");
        }
        __builtin_amdgcn_s_barrier();
        asm volatile("" ::: "memory");
        __builtin_amdgcn_sched_barrier(0);

        half8 av[4], bf[4];

        // ---- phase 0: bf + ah(rh0); stage Ah(kt+2) ----
#pragma unroll
        for (int j = 0; j < 4; j++) bf[j] = *(const half8*)(Lb + 16384 + boff[j]);
#pragma unroll
        for (int i = 0; i < 4; i++) av[i] = *(const half8*)(Lb + aoff[i]);
        if (pre) { ld16(gAh + nofs, Ld);  ld16(gAh + rstep + nofs, Ld + 4096); }
        __builtin_amdgcn_s_barrier();
        __builtin_amdgcn_s_setprio(1);
#pragma unroll
        for (int i = 0; i < 4; i++)
#pragma unroll
            for (int j = 0; j < 4; j++)
                acc[i][j] = __builtin_amdgcn_mfma_f32_16x16x32_f16(av[i], bf[j], acc[i][j], 0, 0, 0);
        __builtin_amdgcn_s_setprio(0);
        __builtin_amdgcn_s_barrier();

        // ---- phase 1: al(rh0); stage Al(kt+2) ----
#pragma unroll
        for (int i = 0; i < 4; i++) av[i] = *(const half8*)(Lb + 8192 + aoff[i]);
        if (pre) { ld16(gAl + nofs, Ld + 8192);  ld16(gAl + rstep + nofs, Ld + 12288); }
        __builtin_amdgcn_s_barrier();
        __builtin_amdgcn_s_setprio(1);
#pragma unroll
        for (int i = 0; i < 4; i++)
#pragma unroll
            for (int j = 0; j < 4; j++)
                acc[i][j] = __builtin_amdgcn_mfma_f32_16x16x32_f16(av[i], bf[j], acc[i][j], 0, 0, 0);
        __builtin_amdgcn_s_setprio(0);
        __builtin_amdgcn_s_barrier();

        // ---- phase 2: ah(rh1); stage B(kt+2) ----
#pragma unroll
        for (int i = 0; i < 4; i++) av[i] = *(const half8*)(Lb + aoff[4 + i]);
        if (pre) { ld16(gB + nofs, Ld + 16384);  ld16(gB + rstep + nofs, Ld + 20480); }
        __builtin_amdgcn_s_barrier();
        __builtin_amdgcn_s_setprio(1);
#pragma unroll
        for (int i = 0; i < 4; i++)
#pragma unroll
            for (int j = 0; j < 4; j++)
                acc[4 + i][j] = __builtin_amdgcn_mfma_f32_16x16x32_f16(av[i], bf[j], acc[4 + i][j], 0, 0, 0);
        __builtin_amdgcn_s_setprio(0);
        __builtin_amdgcn_s_barrier();

        // ---- phase 3: al(rh1) ----  (tail barrier elided: next head has one)
#pragma unroll
        for (int i = 0; i < 4; i++) av[i] = *(const half8*)(Lb + 8192 + aoff[4 + i]);
        __builtin_amdgcn_s_barrier();
        __builtin_amdgcn_s_setprio(1);
#pragma unroll
        for (int i = 0; i < 4; i++)
#pragma unroll
            for (int j = 0; j < 4; j++)
                acc[4 + i][j] = __builtin_amdgcn_mfma_f32_16x16x32_f16(av[i], bf[j], acc[4 + i][j], 0, 0, 0);
        __builtin_amdgcn_s_setprio(0);
    }

    // C store (f32, coalesced per 16 lanes)
#pragma unroll
    for (int i = 0; i < 8; i++) {
        int row_base = m0 + wr + i * 16 + quad * 4;
#pragma unroll
        for (int j = 0; j < 4; j++) {
            int col = n0 + wc + j * 16 + l15;
#pragma unroll
            for (int r = 0; r < 4; r++)
                C[(int64_t)(row_base + r) * N + col] = acc[i][j][r];
        }
    }

    // fused partial column stats (max & sumexp over this block's 256 rows)
    int wrow = wave >> 2;                   // row-half of the block
#pragma unroll
    for (int j = 0; j < 4; j++) {
        float m = -3.0e38f;
#pragma unroll
        for (int i = 0; i < 8; i++)
#pragma unroll
            for (int r = 0; r < 4; r++) m = fmaxf(m, acc[i][j][r]);
        float s = 0.f;
#pragma unroll
        for (int i = 0; i < 8; i++)
#pragma unroll
            for (int r = 0; r < 4; r++) s += __expf(acc[i][j][r] - m);
#pragma unroll
        for (int d = 16; d <= 32; d <<= 1) {
            float m2 = __shfl_xor(m, d, 64);
            float s2 = __shfl_xor(s, d, 64);
            float nm = fmaxf(m, m2);
            s = s * __expf(m - nm) + s2 * __expf(m2 - nm);
            m = nm;
        }
        if (lane < 16) {
            red_m[wrow][wc + j * 16 + l15] = m;
            red_s[wrow][wc + j * 16 + l15] = s;
        }
    }
    __syncthreads();
    if (t < 256) {
        float ma = red_m[0][t], mb = red_m[1][t];
        float sa = red_s[0][t], sb = red_s[1][t];
        float m = fmaxf(ma, mb);
        float s = sa * __expf(ma - m) + sb * __expf(mb - m);
        int idx = blockIdx.y * (B_ * S_) + b * S_ + n0 + t;
        pm[idx] = m;
        ps[idx] = s;
    }
}

// --------------------------- column softmax --------------------------------

__global__ void k_colstats2(const float* __restrict__ pm, const float* __restrict__ ps,
                            float* __restrict__ cmax, float* __restrict__ cinv)
{
    int i = blockIdx.x * 256 + threadIdx.x;   // 8192
    float m = -3.0e38f;
#pragma unroll
    for (int c = 0; c < 8; c++) m = fmaxf(m, pm[c * (B_ * S_) + i]);
    float sum = 0.f;
#pragma unroll
    for (int c = 0; c < 8; c++) sum += ps[c * (B_ * S_) + i] * __expf(pm[c * (B_ * S_) + i] - m);
    cmax[i] = m;
    cinv[i] = 1.0f / sum;
}

// weight = exp(L - cmax)/csum, in place; also emit f16 copy for the final GEMM
__global__ void k_softmax_norm(float4* __restrict__ L, const float4* __restrict__ cmax4,
                               const float4* __restrict__ cinv4, ushort4* __restrict__ wbf)
{
    const int64_t n4 = (int64_t)B_ * S_ * S_ / 4;
    for (int64_t i = (int64_t)blockIdx.x * blockDim.x + threadIdx.x; i < n4;
         i += (int64_t)gridDim.x * blockDim.x) {
        int b  = (int)(i >> 20);
        int c4 = (int)(i & 511);
        float4 x  = L[i];
        float4 cm = cmax4[b * 512 + c4];
        float4 ci = cinv4[b * 512 + c4];
        float4 w;
        w.x = __expf(x.x - cm.x) * ci.x;
        w.y = __expf(x.y - cm.y) * ci.y;
        w.z = __expf(x.z - cm.z) * ci.z;
        w.w = __expf(x.w - cm.w) * ci.w;
        L[i] = w;
        wbf[i] = (ushort4){f2h(w.x), f2h(w.y), f2h(w.z), f2h(w.w)};
    }
}

// ---------------- dual NT f16 GEMM, 2-phase interleave (R12) ----------------
// Two NT GEMMs (PT and Q) in one 512-block launch; C[m][n] = sum A[m][k]B[n][k].
// 256x128 tile, BK=64, 8 waves 4x2 of 64x64.  Triple-buffered LDS (144KB),
// counted vmcnt(6), prefetch 2 deep, XOR chunk swizzle, 2 phases per K-tile:
// {8 ds_reads + 3 staging ld16, s_barrier, 16 MFMA (setprio), s_barrier}.
// blocks [0,256): PT  M=1024 N=2048 (bx 0..15, by 0..3, b 0..3)
// blocks [256,512): Q M=2048 N=1024 (bx 0..7,  by 0..7, b 0..3)   K=1024 both.
__launch_bounds__(512, 2)
__global__ void k_gemm_nt2(const ushort_t* __restrict__ A0, int lda0, int64_t bsA0,
                           const ushort_t* __restrict__ B0, int ldb0, int64_t bsB0,
                           ushort_t* __restrict__ C0, int ldc0, int64_t bsC0,
                           const ushort_t* __restrict__ A1, int lda1, int64_t bsA1,
                           const ushort_t* __restrict__ B1, int ldb1, int64_t bsB1,
                           ushort_t* __restrict__ C1, int ldc1, int64_t bsC1)
{
    const int K = D_;
    int id = blockIdx.x;
    const ushort_t *A, *Bm;
    ushort_t* C;
    int lda, ldb, ldc, bx, by;
    if (id < 256) {
        int b = id >> 6;
        by = (id >> 4) & 3;  bx = id & 15;
        A = A0 + (int64_t)b * bsA0;  Bm = B0 + (int64_t)b * bsB0;  C = C0 + (int64_t)b * bsC0;
        lda = lda0; ldb = ldb0; ldc = ldc0;
    } else {
        int i2 = id - 256;
        int b = i2 >> 6;
        by = (i2 >> 3) & 7;  bx = i2 & 7;
        A = A1 + (int64_t)b * bsA1;  Bm = B1 + (int64_t)b * bsB1;  C = C1 + (int64_t)b * bsC1;
        lda = lda1; ldb = ldb1; ldc = ldc1;
    }

    __shared__ __align__(16) ushort_t lds[3 * 24576];

    int t    = threadIdx.x;                 // 0..511
    int m0   = by * 256, n0 = bx * 128;
    int wave = t >> 6, lane = t & 63;
    int wr   = (wave >> 1) * 64;            // 0,64,128,192
    int wc   = (wave & 1) * 64;             // 0,64
    int l15  = lane & 15, quad = lane >> 4;

    f32x4 acc[4][4];
#pragma unroll
    for (int i = 0; i < 4; i++)
#pragma unroll
        for (int j = 0; j < 4; j++) acc[i][j] = (f32x4){0.f, 0.f, 0.f, 0.f};

    int srow = t >> 3;                      // 0..63
    int cg   = (t & 7) ^ (srow & 7);
    int scol = cg * 8;

    const ushort_t* gA = A  + (int64_t)(m0 + srow) * lda + scol;
    const ushort_t* gB = Bm + (int64_t)(n0 + srow) * ldb + scol;

    auto stage = [&](int bufi, int k0) {    // prologue only
        ushort_t* Lb = lds + bufi * 24576 + t * 8;
        ld16(gA + k0,                        Lb);
        ld16(gA + (int64_t)64  * lda + k0,   Lb + 4096);
        ld16(gA + (int64_t)128 * lda + k0,   Lb + 8192);
        ld16(gA + (int64_t)192 * lda + k0,   Lb + 12288);
        ld16(gB + k0,                        Lb + 16384);
        ld16(gB + (int64_t)64  * ldb + k0,   Lb + 20480);
    };

    int aoff[4][2], boff[4][2];
#pragma unroll
    for (int i = 0; i < 4; i++) {
        int R = wr + i * 16 + l15;
#pragma unroll
        for (int h = 0; h < 2; h++) {
            int c = quad + h * 4;
            aoff[i][h] = R * 64 + ((c ^ (R & 7)) << 3);
        }
    }
#pragma unroll
    for (int j = 0; j < 4; j++) {
        int R = wc + j * 16 + l15;
#pragma unroll
        for (int h = 0; h < 2; h++) {
            int c = quad + h * 4;
            boff[j][h] = 16384 + R * 64 + ((c ^ (R & 7)) << 3);
        }
    }

    const int NT = K >> 6;                  // 16
    stage(0, 0);
    stage(1, 64);

    for (int kt = 0; kt < NT; ++kt) {
        const ushort_t* Lb = lds + (kt % 3) * 24576;
        ushort_t* Ld = lds + ((kt + 2) % 3) * 24576 + t * 8;
        const int nofs = (kt + 2) * 64;
        const bool pre = (kt + 2) < NT;

        if (kt + 1 < NT) {
            asm volatile("s_waitcnt vmcnt(6)" ::: "memory");
        } else {
            asm volatile("s_waitcnt vmcnt(0)" ::: "memory");
        }
        __builtin_amdgcn_s_barrier();
        asm volatile("" ::: "memory");
        __builtin_amdgcn_sched_barrier(0);

        half8 af[4], bf[4];

        // ---- phase 0 (h=0): reads + stage A rows 0..2 ----
#pragma unroll
        for (int i = 0; i < 4; i++) af[i] = *(const half8*)(Lb + aoff[i][0]);
#pragma unroll
        for (int j = 0; j < 4; j++) bf[j] = *(const half8*)(Lb + boff[j][0]);
        if (pre) {
            ld16(gA + nofs,                      Ld);
            ld16(gA + (int64_t)64  * lda + nofs, Ld + 4096);
            ld16(gA + (int64_t)128 * lda + nofs, Ld + 8192);
        }
        __builtin_amdgcn_s_barrier();
        __builtin_amdgcn_s_setprio(1);
#pragma unroll
        for (int i = 0; i < 4; i++)
#pragma unroll
            for (int j = 0; j < 4; j++)
                acc[i][j] = __builtin_amdgcn_mfma_f32_16x16x32_f16(af[i], bf[j], acc[i][j], 0, 0, 0);
        __builtin_amdgcn_s_setprio(0);
        __builtin_amdgcn_s_barrier();

        // ---- phase 1 (h=1): reads + stage A row 3, B rows 0..1 ----
#pragma unroll
        for (int i = 0; i < 4; i++) af[i] = *(const half8*)(Lb + aoff[i][1]);
#pragma unroll
        for (int j = 0; j < 4; j++) bf[j] = *(const half8*)(Lb + boff[j][1]);
        if (pre) {
            ld16(gA + (int64_t)192 * lda + nofs, Ld + 12288);
            ld16(gB + nofs,                      Ld + 16384);
            ld16(gB + (int64_t)64  * ldb + nofs, Ld + 20480);
        }
        __builtin_amdgcn_s_barrier();
        __builtin_amdgcn_s_setprio(1);
#pragma unroll
        for (int i = 0; i < 4; i++)
#pragma unroll
            for (int j = 0; j < 4; j++)
                acc[i][j] = __builtin_amdgcn_mfma_f32_16x16x32_f16(af[i], bf[j], acc[i][j], 0, 0, 0);
        __builtin_amdgcn_s_setprio(0);
        // tail barrier elided: next iteration head has one
    }

#pragma unroll
    for (int i = 0; i < 4; i++) {
        int row_base = m0 + wr + i * 16 + quad * 4;
#pragma unroll
        for (int j = 0; j < 4; j++) {
            int col = n0 + wc + j * 16 + l15;
#pragma unroll
            for (int r = 0; r < 4; r++)
                C[(int64_t)(row_base + r) * ldc + col] = f2h(acc[i][j][r]);
        }
    }
}

// --------------------------- final GEMM (R12) -------------------------------
// out[b][t][n] = sum_s weight_f16[b][t][s]*PT[b][n][s] + Q[b][t][n] + bias[n]
// 256x128 / BK=64 / 8-wave, 3-buf counted vmcnt(6), 2-phase interleave.
__launch_bounds__(512, 2)
__global__ void k_gemm_final(const ushort_t* __restrict__ Wt, const ushort_t* __restrict__ PT,
                             const ushort_t* __restrict__ Q, const float* __restrict__ bias,
                             float* __restrict__ out)
{
    const int K = S_, N = OUTD;
    int b = blockIdx.z;
    const ushort_t* A  = Wt + (int64_t)b * S_ * S_;
    const ushort_t* Bm = PT + (int64_t)b * OUTD * S_;
    const ushort_t* Qb = Q  + (int64_t)b * S_ * OUTD;
    float* Cb = out + (int64_t)b * S_ * OUTD;

    __shared__ __align__(16) ushort_t lds[3 * 24576];

    int t    = threadIdx.x;
    int m0   = blockIdx.y * 256, n0 = blockIdx.x * 128;
    int wave = t >> 6, lane = t & 63;
    int wr   = (wave >> 1) * 64;
    int wc   = (wave & 1) * 64;
    int l15  = lane & 15, quad = lane >> 4;

    f32x4 acc[4][4];
#pragma unroll
    for (int i = 0; i < 4; i++)
#pragma unroll
        for (int j = 0; j < 4; j++) acc[i][j] = (f32x4){0.f, 0.f, 0.f, 0.f};

    int srow = t >> 3;
    int cg   = (t & 7) ^ (srow & 7);
    int scol = cg * 8;

    const ushort_t* gA = A  + (int64_t)(m0 + srow) * K + scol;
    const ushort_t* gB = Bm + (int64_t)(n0 + srow) * K + scol;

    auto stage = [&](int bufi, int k0) {    // prologue only
        ushort_t* Lb = lds + bufi * 24576 + t * 8;
        ld16(gA + k0,                      Lb);
        ld16(gA + (int64_t)64  * K + k0,   Lb + 4096);
        ld16(gA + (int64_t)128 * K + k0,   Lb + 8192);
        ld16(gA + (int64_t)192 * K + k0,   Lb + 12288);
        ld16(gB + k0,                      Lb + 16384);
        ld16(gB + (int64_t)64  * K + k0,   Lb + 20480);
    };

    int aoff[4][2], boff[4][2];
#pragma unroll
    for (int i = 0; i < 4; i++) {
        int R = wr + i * 16 + l15;
#pragma unroll
        for (int h = 0; h < 2; h++) {
            int c = quad + h * 4;
            aoff[i][h] = R * 64 + ((c ^ (R & 7)) << 3);
        }
    }
#pragma unroll
    for (int j = 0; j < 4; j++) {
        int R = wc + j * 16 + l15;
#pragma unroll
        for (int h = 0; h < 2; h++) {
            int c = quad + h * 4;
            boff[j][h] = 16384 + R * 64 + ((c ^ (R & 7)) << 3);
        }
    }

    const int NT = K >> 6;                  // 32
    stage(0, 0);
    stage(1, 64);

    for (int kt = 0; kt < NT; ++kt) {
        const ushort_t* Lb = lds + (kt % 3) * 24576;
        ushort_t* Ld = lds + ((kt + 2) % 3) * 24576 + t * 8;
        const int nofs = (kt + 2) * 64;
        const bool pre = (kt + 2) < NT;

        if (kt + 1 < NT) {
            asm volatile("s_waitcnt vmcnt(6)" ::: "memory");
        } else {
            asm volatile("s_waitcnt vmcnt(0)" ::: "memory");
        }
        __builtin_amdgcn_s_barrier();
        asm volatile("" ::: "memory");
        __builtin_amdgcn_sched_barrier(0);

        half8 af[4], bf[4];

        // ---- phase 0 (h=0) ----
#pragma unroll
        for (int i = 0; i < 4; i++) af[i] = *(const half8*)(Lb + aoff[i][0]);
#pragma unroll
        for (int j = 0; j < 4; j++) bf[j] = *(const half8*)(Lb + boff[j][0]);
        if (pre) {
            ld16(gA + nofs,                    Ld);
            ld16(gA + (int64_t)64  * K + nofs, Ld + 4096);
            ld16(gA + (int64_t)128 * K + nofs, Ld + 8192);
        }
        __builtin_amdgcn_s_barrier();
        __builtin_amdgcn_s_setprio(1);
#pragma unroll
        for (int i = 0; i < 4; i++)
#pragma unroll
            for (int j = 0; j < 4; j++)
                acc[i][j] = __builtin_amdgcn_mfma_f32_16x16x32_f16(af[i], bf[j], acc[i][j], 0, 0, 0);
        __builtin_amdgcn_s_setprio(0);
        __builtin_amdgcn_s_barrier();

        // ---- phase 1 (h=1) ----
#pragma unroll
        for (int i = 0; i < 4; i++) af[i] = *(const half8*)(Lb + aoff[i][1]);
#pragma unroll
        for (int j = 0; j < 4; j++) bf[j] = *(const half8*)(Lb + boff[j][1]);
        if (pre) {
            ld16(gA + (int64_t)192 * K + nofs, Ld + 12288);
            ld16(gB + nofs,                    Ld + 16384);
            ld16(gB + (int64_t)64  * K + nofs, Ld + 20480);
        }
        __builtin_amdgcn_s_barrier();
        __builtin_amdgcn_s_setprio(1);
#pragma unroll
        for (int i = 0; i < 4; i++)
#pragma unroll
            for (int j = 0; j < 4; j++)
                acc[i][j] = __builtin_amdgcn_mfma_f32_16x16x32_f16(af[i], bf[j], acc[i][j], 0, 0, 0);
        __builtin_amdgcn_s_setprio(0);
        // tail barrier elided: next iteration head has one
    }

#pragma unroll
    for (int i = 0; i < 4; i++) {
        int row_base = m0 + wr + i * 16 + quad * 4;
#pragma unroll
        for (int j = 0; j < 4; j++) {
            int col = n0 + wc + j * 16 + l15;
            float bv = bias[col];
#pragma unroll
            for (int r = 0; r < 4; r++) {
                int64_t idx = (int64_t)(row_base + r) * N + col;
                Cb[idx] = acc[i][j][r] + h2f(Qb[idx]) + bv;
            }
        }
    }
}

// ------------------------------- launcher ----------------------------------

extern "C" void kernel_launch(void* const* d_in, const int* in_sizes, int n_in,
                              void* d_out, int out_size, void* d_ws, size_t ws_size,
                              hipStream_t stream)
{
    const float* src  = (const float*)d_in[0];
    const float* tgt  = (const float*)d_in[1];
    const float* W    = (const float*)d_in[2];
    const float* bias = (const float*)d_in[3];

    float* out = (float*)d_out;                           // [4,2048,1024]
    float* Lw  = out + (size_t)B_ * S_ * OUTD;            // [4,2048,2048] logits -> weight

    char*  ws = (char*)d_ws;
    size_t o  = 0;
    auto take = [&](size_t bytes) -> char* {
        char* p = ws + o;
        o += (bytes + 255) & ~(size_t)255;
        return p;
    };
    const size_t ELEMS = (size_t)B_ * S_ * D_;            // 8,388,608
    ushort_t* sh   = (ushort_t*)take(ELEMS * 2);          // src f16
    ushort_t* th   = (ushort_t*)take(ELEMS * 2);          // tgt hi f16
    ushort_t* tl   = (ushort_t*)take(ELEMS * 2);          // tgt lo f16
    ushort_t* wbf  = (ushort_t*)take((size_t)B_ * S_ * S_ * 2);     // weight f16
    ushort_t* wb   = (ushort_t*)take((size_t)OUTD * 2 * D_ * 2);    // W f16 [1024,2048]
    ushort_t* PT   = (ushort_t*)take((size_t)B_ * OUTD * S_ * 2);   // W1@src^T f16 [b,1024,2048]
    ushort_t* Qb   = (ushort_t*)take((size_t)B_ * S_ * OUTD * 2);   // tgt@W2^T f16 [b,2048,1024]
    float*    pm   = (float*)take(16 * (size_t)B_ * S_ * 4);
    float*    ps   = (float*)take(16 * (size_t)B_ * S_ * 4);
    float*    cmax = (float*)take((size_t)B_ * S_ * 4);
    float*    cinv = (float*)take((size_t)B_ * S_ * 4);
    (void)ws_size; (void)in_sizes; (void)n_in; (void)out_size;

    // fused: src/tgt f16 split + W f16 convert
    k_split<<<dim3(2560), dim3(256), 0, stream>>>(
        (const float4*)src, (const float4*)tgt, (const float4*)W,
        (ushort4*)sh, (ushort4*)th, (ushort4*)tl, (ushort4*)wb);

    // dual GEMM: PT[b][n][s] = sum_d W1[n][d]*src[b][s][d]  (blocks 0..255)
    //            Q[b][t][n]  = sum_d tgt[b][t][d]*W2[n][d]  (blocks 256..511)
    k_gemm_nt2<<<dim3(512), dim3(512), 0, stream>>>(
        wb, 2 * D_, 0,  sh, D_, (int64_t)S_ * D_,  PT, S_, (int64_t)OUTD * S_,
        th, D_, (int64_t)S_ * D_,  wb + D_, 2 * D_, 0,  Qb, OUTD, (int64_t)S_ * OUTD);

    k_gemm_logits<<<dim3(8, 8, 4), dim3(512), 0, stream>>>(th, tl, sh, Lw, pm, ps);

    k_colstats2<<<dim3(32), dim3(256), 0, stream>>>(pm, ps, cmax, cinv);
    k_softmax_norm<<<dim3(2048), dim3(256), 0, stream>>>((float4*)Lw, (const float4*)cmax,
                                                         (const float4*)cinv, (ushort4*)wbf);

    k_gemm_final<<<dim3(8, 8, 4), dim3(512), 0, stream>>>(wbf, PT, Qb, bias, out);
}

// Round 7
// 327.248 us; speedup vs baseline: 1.0748x; 1.0377x over previous
//
#include <hip/hip_runtime.h>
#include <stdint.h>

// ---------------------------------------------------------------------------
// Attention_18116172054662 on MI355X (gfx950)
//   L = tgt @ src^T  (2-term split-f16: (tgt_hi + tgt_lo) @ src_f16)
//   weight = softmax(L, axis=tgt)   -> second output (f32, in place in d_out)
//   out = weight @ PT^T + Q + b  where  PT = W1 @ src^T,  Q = tgt @ W2^T
// R7: XOR chunk swizzle (slot = chunk ^ (row&7)) kills 128B-row bank wrap.
// R8: 256x256 / 8-wave / dbuf-prefetch template (conflicts 6.3M -> 0).
// R9: ported to PT/Q/final (256x128, BK=64). 358 -> 348.
// R10: counted vmcnt(6), 3 LDS bufs, 2-deep prefetch (neutral on 1-phase).
// R11: logits 4-phase interleave: 86 -> 77 us, MfmaUtil 32 -> 37%.
// R12: 2-phase interleave in nt2/final; dual-nt2 single launch; wconv fused
//     into split. 348 -> 339.6.
// R13: T1 XCD-aware block swizzle in all GEMMs: cluster A-panel sharers on
//     one XCD -> panel re-reads become same-L2 hits (logits FETCH 139MB vs
//     48MB inputs = 2.9x amplification). Nontemporal stores for
//     never-re-read f32 outputs.  (R13b: fix nontemporal f32x4 cast.)
// ---------------------------------------------------------------------------

#define B_   4
#define S_   2048
#define D_   1024
#define OUTD 1024

typedef unsigned short ushort_t;
typedef _Float16 half8 __attribute__((ext_vector_type(8)));
typedef float    f32x4 __attribute__((ext_vector_type(4)));

__device__ __forceinline__ ushort_t f2h(float f) {
    union { _Float16 h; ushort_t u; } v;
    v.h = (_Float16)f;                    // RNE
    return v.u;
}
__device__ __forceinline__ float h2f(ushort_t u) {
    union { _Float16 h; ushort_t u; } v;
    v.u = u;
    return (float)v.h;
}

// async global->LDS, 16B per lane; LDS dest = wave-uniform base + lane*16
__device__ __forceinline__ void ld16(const ushort_t* g, ushort_t* l) {
    __builtin_amdgcn_global_load_lds(
        (const __attribute__((address_space(1))) void*)g,
        (__attribute__((address_space(3))) void*)l, 16, 0, 0);
}

// --------------------------- elementwise prep ------------------------------

// src -> f16; tgt -> f16 hi + f16 lo; W -> f16 (fused)
__global__ void k_split(const float4* __restrict__ src, const float4* __restrict__ tgt,
                        const float4* __restrict__ W,
                        ushort4* __restrict__ sh,
                        ushort4* __restrict__ th, ushort4* __restrict__ tl,
                        ushort4* __restrict__ wb)
{
    const int64_t n4 = (int64_t)B_ * S_ * D_ / 4;         // 2,097,152
    const int64_t w4 = (int64_t)OUTD * 2 * D_ / 4;        //   524,288
    for (int64_t i = (int64_t)blockIdx.x * blockDim.x + threadIdx.x; i < n4 + w4;
         i += (int64_t)gridDim.x * blockDim.x) {
        if (i < n4) {
            float4 s = src[i];
            sh[i] = (ushort4){f2h(s.x), f2h(s.y), f2h(s.z), f2h(s.w)};
            float4 tv = tgt[i];
            ushort4 ht = {f2h(tv.x), f2h(tv.y), f2h(tv.z), f2h(tv.w)};
            th[i] = ht;
            tl[i] = (ushort4){f2h(tv.x - h2f(ht.x)), f2h(tv.y - h2f(ht.y)),
                              f2h(tv.z - h2f(ht.z)), f2h(tv.w - h2f(ht.w))};
        } else {
            int64_t j = i - n4;
            float4 w = W[j];
            wb[j] = (ushort4){f2h(w.x), f2h(w.y), f2h(w.z), f2h(w.w)};
        }
    }
}

// ------------------------------- GEMM 1 ------------------------------------
// L[b] = tgt[b] @ src[b]^T, 2-term f16 split:  Ah*B + Al*B
// 256x256 tile, BK=32, 8 waves 2Mx4N of 128x64, 16x16x32 f16 MFMA.
// Triple-buffered LDS, counted vmcnt(6), prefetch 2 deep, 4-phase interleave.
// R13: XCD swizzle — A-panel sharers (same by,b; bx=0..7) share wg&7 -> XCD.
__launch_bounds__(512, 2)
__global__ void k_gemm_logits(const ushort_t* __restrict__ Ah, const ushort_t* __restrict__ Al,
                              const ushort_t* __restrict__ Bs,
                              float* __restrict__ C,
                              float* __restrict__ pm, float* __restrict__ ps)
{
    const int M = S_, N = S_, K = D_;
    // XCD swizzle decode: wg = (g&7) + 8*bx + 64*(g>>3), g = by + 8*b
    int wg = blockIdx.x + 8 * blockIdx.y + 64 * blockIdx.z;   // 0..255
    int bx = (wg >> 3) & 7;
    int g  = (wg & 7) + 8 * (wg >> 6);
    int by = g & 7;
    int b  = g >> 3;

    Ah += (int64_t)b * M * K;  Al += (int64_t)b * M * K;
    Bs += (int64_t)b * N * K;
    C  += (int64_t)b * M * N;

    // 3 bufs x { Ah 16KB | Al 16KB | B 16KB }  (ushort units; 144 KiB total)
    __shared__ __align__(16) ushort_t lds[3 * 24576];
    __shared__ float red_m[2][256], red_s[2][256];

    int t    = threadIdx.x;                 // 0..511
    int m0   = by * 256, n0 = bx * 256;
    int wave = t >> 6, lane = t & 63;
    int wr   = (wave >> 2) * 128;           // 0,128
    int wc   = (wave & 3) * 64;             // 0,64,128,192
    int l15  = lane & 15, quad = lane >> 4;

    f32x4 acc[8][4];
#pragma unroll
    for (int i = 0; i < 8; i++)
#pragma unroll
        for (int j = 0; j < 4; j++) acc[i][j] = (f32x4){0.f, 0.f, 0.f, 0.f};

    int pr   = t >> 3;                      // paired-row 0..63 within pass
    int slot = t & 7;
    int cg   = slot ^ (pr & 7);
    int srow = pr * 2 + (cg >> 2);          // 0..127 (+128 for pass 1)
    int scol = (cg & 3) * 8;                // f16 col within BK=32

    const ushort_t* gAh = Ah + (int64_t)(m0 + srow) * K + scol;
    const ushort_t* gAl = Al + (int64_t)(m0 + srow) * K + scol;
    const ushort_t* gB  = Bs + (int64_t)(n0 + srow) * K + scol;
    const int64_t rstep = (int64_t)128 * K;     // pass-1 global row offset

    auto stage_all = [&](int bufi, int kofs) {  // prologue only
        ushort_t* Lb = lds + bufi * 24576 + t * 8;
        ld16(gAh + kofs,         Lb);
        ld16(gAh + rstep + kofs, Lb + 4096);
        ld16(gAl + kofs,         Lb + 8192);
        ld16(gAl + rstep + kofs, Lb + 12288);
        ld16(gB  + kofs,         Lb + 16384);
        ld16(gB  + rstep + kofs, Lb + 20480);
    };

    int aoff[8], boff[4];
#pragma unroll
    for (int i = 0; i < 8; i++) {
        int R = wr + i * 16 + l15;
        int p = R >> 1, c = ((R & 1) << 2) + quad;
        aoff[i] = p * 64 + ((c ^ (p & 7)) << 3);
    }
#pragma unroll
    for (int j = 0; j < 4; j++) {
        int R = wc + j * 16 + l15;
        int p = R >> 1, c = ((R & 1) << 2) + quad;
        boff[j] = p * 64 + ((c ^ (p & 7)) << 3);
    }

    const int NT = 32;
    stage_all(0, 0);                        // prologue: tiles 0 and 1 in flight
    stage_all(1, 32);

    for (int kt = 0; kt < NT; ++kt) {
        const ushort_t* Lb = lds + (kt % 3) * 24576;
        ushort_t* Ld = lds + ((kt + 2) % 3) * 24576 + t * 8;
        const int nofs = (kt + 2) * 32;
        const bool pre = (kt + 2) < NT;

        if (kt + 1 < NT) {
            asm volatile("s_waitcnt vmcnt(6)" ::: "memory");
        } else {
            asm volatile("s_waitcnt vmcnt(0)" ::: "memory");
        }
        __builtin_amdgcn_s_barrier();
        asm volatile("" ::: "memory");
        __builtin_amdgcn_sched_barrier(0);

        half8 av[4], bf[4];

        // ---- phase 0: bf + ah(rh0); stage Ah(kt+2) ----
#pragma unroll
        for (int j = 0; j < 4; j++) bf[j] = *(const half8*)(Lb + 16384 + boff[j]);
#pragma unroll
        for (int i = 0; i < 4; i++) av[i] = *(const half8*)(Lb + aoff[i]);
        if (pre) { ld16(gAh + nofs, Ld);  ld16(gAh + rstep + nofs, Ld + 4096); }
        __builtin_amdgcn_s_barrier();
        __builtin_amdgcn_s_setprio(1);
#pragma unroll
        for (int i = 0; i < 4; i++)
#pragma unroll
            for (int j = 0; j < 4; j++)
                acc[i][j] = __builtin_amdgcn_mfma_f32_16x16x32_f16(av[i], bf[j], acc[i][j], 0, 0, 0);
        __builtin_amdgcn_s_setprio(0);
        __builtin_amdgcn_s_barrier();

        // ---- phase 1: al(rh0); stage Al(kt+2) ----
#pragma unroll
        for (int i = 0; i < 4; i++) av[i] = *(const half8*)(Lb + 8192 + aoff[i]);
        if (pre) { ld16(gAl + nofs, Ld + 8192);  ld16(gAl + rstep + nofs, Ld + 12288); }
        __builtin_amdgcn_s_barrier();
        __builtin_amdgcn_s_setprio(1);
#pragma unroll
        for (int i = 0; i < 4; i++)
#pragma unroll
            for (int j = 0; j < 4; j++)
                acc[i][j] = __builtin_amdgcn_mfma_f32_16x16x32_f16(av[i], bf[j], acc[i][j], 0, 0, 0);
        __builtin_amdgcn_s_setprio(0);
        __builtin_amdgcn_s_barrier();

        // ---- phase 2: ah(rh1); stage B(kt+2) ----
#pragma unroll
        for (int i = 0; i < 4; i++) av[i] = *(const half8*)(Lb + aoff[4 + i]);
        if (pre) { ld16(gB + nofs, Ld + 16384);  ld16(gB + rstep + nofs, Ld + 20480); }
        __builtin_amdgcn_s_barrier();
        __builtin_amdgcn_s_setprio(1);
#pragma unroll
        for (int i = 0; i < 4; i++)
#pragma unroll
            for (int j = 0; j < 4; j++)
                acc[4 + i][j] = __builtin_amdgcn_mfma_f32_16x16x32_f16(av[i], bf[j], acc[4 + i][j], 0, 0, 0);
        __builtin_amdgcn_s_setprio(0);
        __builtin_amdgcn_s_barrier();

        // ---- phase 3: al(rh1) ----  (tail barrier elided: next head has one)
#pragma unroll
        for (int i = 0; i < 4; i++) av[i] = *(const half8*)(Lb + 8192 + aoff[4 + i]);
        __builtin_amdgcn_s_barrier();
        __builtin_amdgcn_s_setprio(1);
#pragma unroll
        for (int i = 0; i < 4; i++)
#pragma unroll
            for (int j = 0; j < 4; j++)
                acc[4 + i][j] = __builtin_amdgcn_mfma_f32_16x16x32_f16(av[i], bf[j], acc[4 + i][j], 0, 0, 0);
        __builtin_amdgcn_s_setprio(0);
    }

    // C store (f32, coalesced per 16 lanes)
#pragma unroll
    for (int i = 0; i < 8; i++) {
        int row_base = m0 + wr + i * 16 + quad * 4;
#pragma unroll
        for (int j = 0; j < 4; j++) {
            int col = n0 + wc + j * 16 + l15;
#pragma unroll
            for (int r = 0; r < 4; r++)
                C[(int64_t)(row_base + r) * N + col] = acc[i][j][r];
        }
    }

    // fused partial column stats (max & sumexp over this block's 256 rows)
    int wrow = wave >> 2;                   // row-half of the block
#pragma unroll
    for (int j = 0; j < 4; j++) {
        float m = -3.0e38f;
#pragma unroll
        for (int i = 0; i < 8; i++)
#pragma unroll
            for (int r = 0; r < 4; r++) m = fmaxf(m, acc[i][j][r]);
        float s = 0.f;
#pragma unroll
        for (int i = 0; i < 8; i++)
#pragma unroll
            for (int r = 0; r < 4; r++) s += __expf(acc[i][j][r] - m);
#pragma unroll
        for (int d = 16; d <= 32; d <<= 1) {
            float m2 = __shfl_xor(m, d, 64);
            float s2 = __shfl_xor(s, d, 64);
            float nm = fmaxf(m, m2);
            s = s * __expf(m - nm) + s2 * __expf(m2 - nm);
            m = nm;
        }
        if (lane < 16) {
            red_m[wrow][wc + j * 16 + l15] = m;
            red_s[wrow][wc + j * 16 + l15] = s;
        }
    }
    __syncthreads();
    if (t < 256) {
        float ma = red_m[0][t], mb = red_m[1][t];
        float sa = red_s[0][t], sb = red_s[1][t];
        float m = fmaxf(ma, mb);
        float s = sa * __expf(ma - m) + sb * __expf(mb - m);
        int idx = by * (B_ * S_) + b * S_ + n0 + t;    // decoded by, not blockIdx.y
        pm[idx] = m;
        ps[idx] = s;
    }
}

// --------------------------- column softmax --------------------------------

__global__ void k_colstats2(const float* __restrict__ pm, const float* __restrict__ ps,
                            float* __restrict__ cmax, float* __restrict__ cinv)
{
    int i = blockIdx.x * 256 + threadIdx.x;   // 8192
    float m = -3.0e38f;
#pragma unroll
    for (int c = 0; c < 8; c++) m = fmaxf(m, pm[c * (B_ * S_) + i]);
    float sum = 0.f;
#pragma unroll
    for (int c = 0; c < 8; c++) sum += ps[c * (B_ * S_) + i] * __expf(pm[c * (B_ * S_) + i] - m);
    cmax[i] = m;
    cinv[i] = 1.0f / sum;
}

// weight = exp(L - cmax)/csum, in place; also emit f16 copy for the final GEMM
__global__ void k_softmax_norm(float4* __restrict__ L, const float4* __restrict__ cmax4,
                               const float4* __restrict__ cinv4, ushort4* __restrict__ wbf)
{
    const int64_t n4 = (int64_t)B_ * S_ * S_ / 4;
    for (int64_t i = (int64_t)blockIdx.x * blockDim.x + threadIdx.x; i < n4;
         i += (int64_t)gridDim.x * blockDim.x) {
        int b  = (int)(i >> 20);
        int c4 = (int)(i & 511);
        float4 x  = L[i];
        float4 cm = cmax4[b * 512 + c4];
        float4 ci = cinv4[b * 512 + c4];
        f32x4 w;
        w.x = __expf(x.x - cm.x) * ci.x;
        w.y = __expf(x.y - cm.y) * ci.y;
        w.z = __expf(x.z - cm.z) * ci.z;
        w.w = __expf(x.w - cm.w) * ci.w;
        __builtin_nontemporal_store(w, (f32x4*)&L[i]);  // w f32: never re-read
        wbf[i] = (ushort4){f2h(w.x), f2h(w.y), f2h(w.z), f2h(w.w)};
    }
}

// ---------------- dual NT f16 GEMM, 2-phase interleave ----------------------
// Two NT GEMMs (PT and Q) in one 512-block launch; C[m][n] = sum A[m][k]B[n][k].
// 256x128 tile, BK=64, 8 waves 4x2 of 64x64.  3-buf LDS, counted vmcnt(6),
// prefetch 2 deep, XOR chunk swizzle, 2 phases per K-tile.
// R13 XCD swizzle per half: A-panel sharers share id&7 (XCD).
//   PT half (id<256):  g = (id&7) + 8*(id>>7), bx = (id>>3)&15
//   Q  half (id>=256): g = (i2&7) + 8*(i2>>6), bx = (i2>>3)&7
__launch_bounds__(512, 2)
__global__ void k_gemm_nt2(const ushort_t* __restrict__ A0, int lda0, int64_t bsA0,
                           const ushort_t* __restrict__ B0, int ldb0, int64_t bsB0,
                           ushort_t* __restrict__ C0, int ldc0, int64_t bsC0,
                           const ushort_t* __restrict__ A1, int lda1, int64_t bsA1,
                           const ushort_t* __restrict__ B1, int ldb1, int64_t bsB1,
                           ushort_t* __restrict__ C1, int ldc1, int64_t bsC1)
{
    const int K = D_;
    int id = blockIdx.x;
    const ushort_t *A, *Bm;
    ushort_t* C;
    int lda, ldb, ldc, bx, by;
    if (id < 256) {
        int g = (id & 7) + 8 * (id >> 7);           // 0..15
        bx = (id >> 3) & 15;                        // 0..15
        by = g & 3;
        int b = g >> 2;
        A = A0 + (int64_t)b * bsA0;  Bm = B0 + (int64_t)b * bsB0;  C = C0 + (int64_t)b * bsC0;
        lda = lda0; ldb = ldb0; ldc = ldc0;
    } else {
        int i2 = id - 256;
        int g = (i2 & 7) + 8 * (i2 >> 6);           // 0..31
        bx = (i2 >> 3) & 7;                         // 0..7
        by = g & 7;
        int b = g >> 3;
        A = A1 + (int64_t)b * bsA1;  Bm = B1 + (int64_t)b * bsB1;  C = C1 + (int64_t)b * bsC1;
        lda = lda1; ldb = ldb1; ldc = ldc1;
    }

    __shared__ __align__(16) ushort_t lds[3 * 24576];

    int t    = threadIdx.x;                 // 0..511
    int m0   = by * 256, n0 = bx * 128;
    int wave = t >> 6, lane = t & 63;
    int wr   = (wave >> 1) * 64;            // 0,64,128,192
    int wc   = (wave & 1) * 64;             // 0,64
    int l15  = lane & 15, quad = lane >> 4;

    f32x4 acc[4][4];
#pragma unroll
    for (int i = 0; i < 4; i++)
#pragma unroll
        for (int j = 0; j < 4; j++) acc[i][j] = (f32x4){0.f, 0.f, 0.f, 0.f};

    int srow = t >> 3;                      // 0..63
    int cg   = (t & 7) ^ (srow & 7);
    int scol = cg * 8;

    const ushort_t* gA = A  + (int64_t)(m0 + srow) * lda + scol;
    const ushort_t* gB = Bm + (int64_t)(n0 + srow) * ldb + scol;

    auto stage = [&](int bufi, int k0) {    // prologue only
        ushort_t* Lb = lds + bufi * 24576 + t * 8;
        ld16(gA + k0,                        Lb);
        ld16(gA + (int64_t)64  * lda + k0,   Lb + 4096);
        ld16(gA + (int64_t)128 * lda + k0,   Lb + 8192);
        ld16(gA + (int64_t)192 * lda + k0,   Lb + 12288);
        ld16(gB + k0,                        Lb + 16384);
        ld16(gB + (int64_t)64  * ldb + k0,   Lb + 20480);
    };

    int aoff[4][2], boff[4][2];
#pragma unroll
    for (int i = 0; i < 4; i++) {
        int R = wr + i * 16 + l15;
#pragma unroll
        for (int h = 0; h < 2; h++) {
            int c = quad + h * 4;
            aoff[i][h] = R * 64 + ((c ^ (R & 7)) << 3);
        }
    }
#pragma unroll
    for (int j = 0; j < 4; j++) {
        int R = wc + j * 16 + l15;
#pragma unroll
        for (int h = 0; h < 2; h++) {
            int c = quad + h * 4;
            boff[j][h] = 16384 + R * 64 + ((c ^ (R & 7)) << 3);
        }
    }

    const int NT = K >> 6;                  // 16
    stage(0, 0);
    stage(1, 64);

    for (int kt = 0; kt < NT; ++kt) {
        const ushort_t* Lb = lds + (kt % 3) * 24576;
        ushort_t* Ld = lds + ((kt + 2) % 3) * 24576 + t * 8;
        const int nofs = (kt + 2) * 64;
        const bool pre = (kt + 2) < NT;

        if (kt + 1 < NT) {
            asm volatile("s_waitcnt vmcnt(6)" ::: "memory");
        } else {
            asm volatile("s_waitcnt vmcnt(0)" ::: "memory");
        }
        __builtin_amdgcn_s_barrier();
        asm volatile("" ::: "memory");
        __builtin_amdgcn_sched_barrier(0);

        half8 af[4], bf[4];

        // ---- phase 0 (h=0): reads + stage A rows 0..2 ----
#pragma unroll
        for (int i = 0; i < 4; i++) af[i] = *(const half8*)(Lb + aoff[i][0]);
#pragma unroll
        for (int j = 0; j < 4; j++) bf[j] = *(const half8*)(Lb + boff[j][0]);
        if (pre) {
            ld16(gA + nofs,                      Ld);
            ld16(gA + (int64_t)64  * lda + nofs, Ld + 4096);
            ld16(gA + (int64_t)128 * lda + nofs, Ld + 8192);
        }
        __builtin_amdgcn_s_barrier();
        __builtin_amdgcn_s_setprio(1);
#pragma unroll
        for (int i = 0; i < 4; i++)
#pragma unroll
            for (int j = 0; j < 4; j++)
                acc[i][j] = __builtin_amdgcn_mfma_f32_16x16x32_f16(af[i], bf[j], acc[i][j], 0, 0, 0);
        __builtin_amdgcn_s_setprio(0);
        __builtin_amdgcn_s_barrier();

        // ---- phase 1 (h=1): reads + stage A row 3, B rows 0..1 ----
#pragma unroll
        for (int i = 0; i < 4; i++) af[i] = *(const half8*)(Lb + aoff[i][1]);
#pragma unroll
        for (int j = 0; j < 4; j++) bf[j] = *(const half8*)(Lb + boff[j][1]);
        if (pre) {
            ld16(gA + (int64_t)192 * lda + nofs, Ld + 12288);
            ld16(gB + nofs,                      Ld + 16384);
            ld16(gB + (int64_t)64  * ldb + nofs, Ld + 20480);
        }
        __builtin_amdgcn_s_barrier();
        __builtin_amdgcn_s_setprio(1);
#pragma unroll
        for (int i = 0; i < 4; i++)
#pragma unroll
            for (int j = 0; j < 4; j++)
                acc[i][j] = __builtin_amdgcn_mfma_f32_16x16x32_f16(af[i], bf[j], acc[i][j], 0, 0, 0);
        __builtin_amdgcn_s_setprio(0);
        // tail barrier elided: next iteration head has one
    }

#pragma unroll
    for (int i = 0; i < 4; i++) {
        int row_base = m0 + wr + i * 16 + quad * 4;
#pragma unroll
        for (int j = 0; j < 4; j++) {
            int col = n0 + wc + j * 16 + l15;
#pragma unroll
            for (int r = 0; r < 4; r++)
                C[(int64_t)(row_base + r) * ldc + col] = f2h(acc[i][j][r]);
        }
    }
}

// --------------------------- final GEMM -------------------------------------
// out[b][t][n] = sum_s weight_f16[b][t][s]*PT[b][n][s] + Q[b][t][n] + bias[n]
// 256x128 / BK=64 / 8-wave, 3-buf counted vmcnt(6), 2-phase interleave.
// R13 XCD swizzle: wg = (g&7) + 8*bx + 64*(g>>3), g = by + 8*b.
__launch_bounds__(512, 2)
__global__ void k_gemm_final(const ushort_t* __restrict__ Wt, const ushort_t* __restrict__ PT,
                             const ushort_t* __restrict__ Q, const float* __restrict__ bias,
                             float* __restrict__ out)
{
    const int K = S_, N = OUTD;
    int wg = blockIdx.x + 8 * blockIdx.y + 64 * blockIdx.z;   // 0..255
    int bx = (wg >> 3) & 7;
    int g  = (wg & 7) + 8 * (wg >> 6);
    int by = g & 7;
    int b  = g >> 3;

    const ushort_t* A  = Wt + (int64_t)b * S_ * S_;
    const ushort_t* Bm = PT + (int64_t)b * OUTD * S_;
    const ushort_t* Qb = Q  + (int64_t)b * S_ * OUTD;
    float* Cb = out + (int64_t)b * S_ * OUTD;

    __shared__ __align__(16) ushort_t lds[3 * 24576];

    int t    = threadIdx.x;
    int m0   = by * 256, n0 = bx * 128;
    int wave = t >> 6, lane = t & 63;
    int wr   = (wave >> 1) * 64;
    int wc   = (wave & 1) * 64;
    int l15  = lane & 15, quad = lane >> 4;

    f32x4 acc[4][4];
#pragma unroll
    for (int i = 0; i < 4; i++)
#pragma unroll
        for (int j = 0; j < 4; j++) acc[i][j] = (f32x4){0.f, 0.f, 0.f, 0.f};

    int srow = t >> 3;
    int cg   = (t & 7) ^ (srow & 7);
    int scol = cg * 8;

    const ushort_t* gA = A  + (int64_t)(m0 + srow) * K + scol;
    const ushort_t* gB = Bm + (int64_t)(n0 + srow) * K + scol;

    auto stage = [&](int bufi, int k0) {    // prologue only
        ushort_t* Lb = lds + bufi * 24576 + t * 8;
        ld16(gA + k0,                      Lb);
        ld16(gA + (int64_t)64  * K + k0,   Lb + 4096);
        ld16(gA + (int64_t)128 * K + k0,   Lb + 8192);
        ld16(gA + (int64_t)192 * K + k0,   Lb + 12288);
        ld16(gB + k0,                      Lb + 16384);
        ld16(gB + (int64_t)64  * K + k0,   Lb + 20480);
    };

    int aoff[4][2], boff[4][2];
#pragma unroll
    for (int i = 0; i < 4; i++) {
        int R = wr + i * 16 + l15;
#pragma unroll
        for (int h = 0; h < 2; h++) {
            int c = quad + h * 4;
            aoff[i][h] = R * 64 + ((c ^ (R & 7)) << 3);
        }
    }
#pragma unroll
    for (int j = 0; j < 4; j++) {
        int R = wc + j * 16 + l15;
#pragma unroll
        for (int h = 0; h < 2; h++) {
            int c = quad + h * 4;
            boff[j][h] = 16384 + R * 64 + ((c ^ (R & 7)) << 3);
        }
    }

    const int NT = K >> 6;                  // 32
    stage(0, 0);
    stage(1, 64);

    for (int kt = 0; kt < NT; ++kt) {
        const ushort_t* Lb = lds + (kt % 3) * 24576;
        ushort_t* Ld = lds + ((kt + 2) % 3) * 24576 + t * 8;
        const int nofs = (kt + 2) * 64;
        const bool pre = (kt + 2) < NT;

        if (kt + 1 < NT) {
            asm volatile("s_waitcnt vmcnt(6)" ::: "memory");
        } else {
            asm volatile("s_waitcnt vmcnt(0)" ::: "memory");
        }
        __builtin_amdgcn_s_barrier();
        asm volatile("" ::: "memory");
        __builtin_amdgcn_sched_barrier(0);

        half8 af[4], bf[4];

        // ---- phase 0 (h=0) ----
#pragma unroll
        for (int i = 0; i < 4; i++) af[i] = *(const half8*)(Lb + aoff[i][0]);
#pragma unroll
        for (int j = 0; j < 4; j++) bf[j] = *(const half8*)(Lb + boff[j][0]);
        if (pre) {
            ld16(gA + nofs,                    Ld);
            ld16(gA + (int64_t)64  * K + nofs, Ld + 4096);
            ld16(gA + (int64_t)128 * K + nofs, Ld + 8192);
        }
        __builtin_amdgcn_s_barrier();
        __builtin_amdgcn_s_setprio(1);
#pragma unroll
        for (int i = 0; i < 4; i++)
#pragma unroll
            for (int j = 0; j < 4; j++)
                acc[i][j] = __builtin_amdgcn_mfma_f32_16x16x32_f16(af[i], bf[j], acc[i][j], 0, 0, 0);
        __builtin_amdgcn_s_setprio(0);
        __builtin_amdgcn_s_barrier();

        // ---- phase 1 (h=1) ----
#pragma unroll
        for (int i = 0; i < 4; i++) af[i] = *(const half8*)(Lb + aoff[i][1]);
#pragma unroll
        for (int j = 0; j < 4; j++) bf[j] = *(const half8*)(Lb + boff[j][1]);
        if (pre) {
            ld16(gA + (int64_t)192 * K + nofs, Ld + 12288);
            ld16(gB + nofs,                    Ld + 16384);
            ld16(gB + (int64_t)64  * K + nofs, Ld + 20480);
        }
        __builtin_amdgcn_s_barrier();
        __builtin_amdgcn_s_setprio(1);
#pragma unroll
        for (int i = 0; i < 4; i++)
#pragma unroll
            for (int j = 0; j < 4; j++)
                acc[i][j] = __builtin_amdgcn_mfma_f32_16x16x32_f16(af[i], bf[j], acc[i][j], 0, 0, 0);
        __builtin_amdgcn_s_setprio(0);
        // tail barrier elided: next iteration head has one
    }

#pragma unroll
    for (int i = 0; i < 4; i++) {
        int row_base = m0 + wr + i * 16 + quad * 4;
#pragma unroll
        for (int j = 0; j < 4; j++) {
            int col = n0 + wc + j * 16 + l15;
            float bv = bias[col];
#pragma unroll
            for (int r = 0; r < 4; r++) {
                int64_t idx = (int64_t)(row_base + r) * N + col;
                float v = acc[i][j][r] + h2f(Qb[idx]) + bv;
                __builtin_nontemporal_store(v, &Cb[idx]);   // out: never re-read
            }
        }
    }
}

// ------------------------------- launcher ----------------------------------

extern "C" void kernel_launch(void* const* d_in, const int* in_sizes, int n_in,
                              void* d_out, int out_size, void* d_ws, size_t ws_size,
                              hipStream_t stream)
{
    const float* src  = (const float*)d_in[0];
    const float* tgt  = (const float*)d_in[1];
    const float* W    = (const float*)d_in[2];
    const float* bias = (const float*)d_in[3];

    float* out = (float*)d_out;                           // [4,2048,1024]
    float* Lw  = out + (size_t)B_ * S_ * OUTD;            // [4,2048,2048] logits -> weight

    char*  ws = (char*)d_ws;
    size_t o  = 0;
    auto take = [&](size_t bytes) -> char* {
        char* p = ws + o;
        o += (bytes + 255) & ~(size_t)255;
        return p;
    };
    const size_t ELEMS = (size_t)B_ * S_ * D_;            // 8,388,608
    ushort_t* sh   = (ushort_t*)take(ELEMS * 2);          // src f16
    ushort_t* th   = (ushort_t*)take(ELEMS * 2);          // tgt hi f16
    ushort_t* tl   = (ushort_t*)take(ELEMS * 2);          // tgt lo f16
    ushort_t* wbf  = (ushort_t*)take((size_t)B_ * S_ * S_ * 2);     // weight f16
    ushort_t* wb   = (ushort_t*)take((size_t)OUTD * 2 * D_ * 2);    // W f16 [1024,2048]
    ushort_t* PT   = (ushort_t*)take((size_t)B_ * OUTD * S_ * 2);   // W1@src^T f16 [b,1024,2048]
    ushort_t* Qb   = (ushort_t*)take((size_t)B_ * S_ * OUTD * 2);   // tgt@W2^T f16 [b,2048,1024]
    float*    pm   = (float*)take(16 * (size_t)B_ * S_ * 4);
    float*    ps   = (float*)take(16 * (size_t)B_ * S_ * 4);
    float*    cmax = (float*)take((size_t)B_ * S_ * 4);
    float*    cinv = (float*)take((size_t)B_ * S_ * 4);
    (void)ws_size; (void)in_sizes; (void)n_in; (void)out_size;

    // fused: src/tgt f16 split + W f16 convert
    k_split<<<dim3(2560), dim3(256), 0, stream>>>(
        (const float4*)src, (const float4*)tgt, (const float4*)W,
        (ushort4*)sh, (ushort4*)th, (ushort4*)tl, (ushort4*)wb);

    // dual GEMM: PT[b][n][s] = sum_d W1[n][d]*src[b][s][d]  (blocks 0..255)
    //            Q[b][t][n]  = sum_d tgt[b][t][d]*W2[n][d]  (blocks 256..511)
    k_gemm_nt2<<<dim3(512), dim3(512), 0, stream>>>(
        wb, 2 * D_, 0,  sh, D_, (int64_t)S_ * D_,  PT, S_, (int64_t)OUTD * S_,
        th, D_, (int64_t)S_ * D_,  wb + D_, 2 * D_, 0,  Qb, OUTD, (int64_t)S_ * OUTD);

    k_gemm_logits<<<dim3(8, 8, 4), dim3(512), 0, stream>>>(th, tl, sh, Lw, pm, ps);

    k_colstats2<<<dim3(32), dim3(256), 0, stream>>>(pm, ps, cmax, cinv);
    k_softmax_norm<<<dim3(2048), dim3(256), 0, stream>>>((float4*)Lw, (const float4*)cmax,
                                                         (const float4*)cinv, (ushort4*)wbf);

    k_gemm_final<<<dim3(8, 8, 4), dim3(512), 0, stream>>>(wbf, PT, Qb, bias, out);
}

// Round 8
// 324.362 us; speedup vs baseline: 1.0844x; 1.0089x over previous
//
#include <hip/hip_runtime.h>
#include <stdint.h>

// ---------------------------------------------------------------------------
// Attention_18116172054662 on MI355X (gfx950)
//   L = tgt @ src^T  (2-term split-f16: (tgt_hi + tgt_lo) @ src_f16)
//   weight = softmax(L, axis=tgt)   -> second output (f32, in place in d_out)
//   out = weight @ PT^T + Q + b  where  PT = W1 @ src^T,  Q = tgt @ W2^T
// R7: XOR chunk swizzle (slot = chunk ^ (row&7)) kills 128B-row bank wrap.
// R8: 256x256 / 8-wave / dbuf-prefetch template (conflicts 6.3M -> 0).
// R9: ported to PT/Q/final (256x128, BK=64). 358 -> 348.
// R10: counted vmcnt, 3 LDS bufs, 2-deep prefetch (neutral on 1-phase).
// R11: logits 4-phase interleave: 86 -> 77 us, MfmaUtil 32 -> 37%.
// R12: 2-phase interleave in nt2/final; dual-nt2 single launch. 348 -> 339.6.
// R13: XCD-aware block swizzle (A-panel sharers -> one XCD): logits FETCH
//     139 -> 82 MB, total 339.6 -> 327.2. Nontemporal f32 stores.
// R14: dual-nt2 -> 256x256 tiles (PT: 4x8x4, Q: 8x4x4 = 256 blocks exactly).
//     256x128 was LDS-read-bound (half the MFMA per staged byte); 256x256
//     restores the logits-class MFMA:LDS ratio. BK=32, 2 phases/tile of
//     16 MFMA, 3-buf 96KB LDS, counted vmcnt(4), per-half bijective XCD
//     swizzle. final unchanged (256x256 would idle half the chip).
// ---------------------------------------------------------------------------

#define B_   4
#define S_   2048
#define D_   1024
#define OUTD 1024

typedef unsigned short ushort_t;
typedef _Float16 half8 __attribute__((ext_vector_type(8)));
typedef float    f32x4 __attribute__((ext_vector_type(4)));

__device__ __forceinline__ ushort_t f2h(float f) {
    union { _Float16 h; ushort_t u; } v;
    v.h = (_Float16)f;                    // RNE
    return v.u;
}
__device__ __forceinline__ float h2f(ushort_t u) {
    union { _Float16 h; ushort_t u; } v;
    v.u = u;
    return (float)v.h;
}

// async global->LDS, 16B per lane; LDS dest = wave-uniform base + lane*16
__device__ __forceinline__ void ld16(const ushort_t* g, ushort_t* l) {
    __builtin_amdgcn_global_load_lds(
        (const __attribute__((address_space(1))) void*)g,
        (__attribute__((address_space(3))) void*)l, 16, 0, 0);
}

// --------------------------- elementwise prep ------------------------------

// src -> f16; tgt -> f16 hi + f16 lo; W -> f16 (fused)
__global__ void k_split(const float4* __restrict__ src, const float4* __restrict__ tgt,
                        const float4* __restrict__ W,
                        ushort4* __restrict__ sh,
                        ushort4* __restrict__ th, ushort4* __restrict__ tl,
                        ushort4* __restrict__ wb)
{
    const int64_t n4 = (int64_t)B_ * S_ * D_ / 4;         // 2,097,152
    const int64_t w4 = (int64_t)OUTD * 2 * D_ / 4;        //   524,288
    for (int64_t i = (int64_t)blockIdx.x * blockDim.x + threadIdx.x; i < n4 + w4;
         i += (int64_t)gridDim.x * blockDim.x) {
        if (i < n4) {
            float4 s = src[i];
            sh[i] = (ushort4){f2h(s.x), f2h(s.y), f2h(s.z), f2h(s.w)};
            float4 tv = tgt[i];
            ushort4 ht = {f2h(tv.x), f2h(tv.y), f2h(tv.z), f2h(tv.w)};
            th[i] = ht;
            tl[i] = (ushort4){f2h(tv.x - h2f(ht.x)), f2h(tv.y - h2f(ht.y)),
                              f2h(tv.z - h2f(ht.z)), f2h(tv.w - h2f(ht.w))};
        } else {
            int64_t j = i - n4;
            float4 w = W[j];
            wb[j] = (ushort4){f2h(w.x), f2h(w.y), f2h(w.z), f2h(w.w)};
        }
    }
}

// ------------------------------- GEMM 1 ------------------------------------
// L[b] = tgt[b] @ src[b]^T, 2-term f16 split:  Ah*B + Al*B
// 256x256 tile, BK=32, 8 waves 2Mx4N of 128x64, 16x16x32 f16 MFMA.
// Triple-buffered LDS, counted vmcnt(6), prefetch 2 deep, 4-phase interleave.
// XCD swizzle: A-panel sharers (same by,b; bx=0..7) share wg&7 -> XCD.
__launch_bounds__(512, 2)
__global__ void k_gemm_logits(const ushort_t* __restrict__ Ah, const ushort_t* __restrict__ Al,
                              const ushort_t* __restrict__ Bs,
                              float* __restrict__ C,
                              float* __restrict__ pm, float* __restrict__ ps)
{
    const int M = S_, N = S_, K = D_;
    // XCD swizzle decode: wg = (g&7) + 8*bx + 64*(g>>3), g = by + 8*b
    int wg = blockIdx.x + 8 * blockIdx.y + 64 * blockIdx.z;   // 0..255
    int bx = (wg >> 3) & 7;
    int g  = (wg & 7) + 8 * (wg >> 6);
    int by = g & 7;
    int b  = g >> 3;

    Ah += (int64_t)b * M * K;  Al += (int64_t)b * M * K;
    Bs += (int64_t)b * N * K;
    C  += (int64_t)b * M * N;

    // 3 bufs x { Ah 16KB | Al 16KB | B 16KB }  (ushort units; 144 KiB total)
    __shared__ __align__(16) ushort_t lds[3 * 24576];
    __shared__ float red_m[2][256], red_s[2][256];

    int t    = threadIdx.x;                 // 0..511
    int m0   = by * 256, n0 = bx * 256;
    int wave = t >> 6, lane = t & 63;
    int wr   = (wave >> 2) * 128;           // 0,128
    int wc   = (wave & 3) * 64;             // 0,64,128,192
    int l15  = lane & 15, quad = lane >> 4;

    f32x4 acc[8][4];
#pragma unroll
    for (int i = 0; i < 8; i++)
#pragma unroll
        for (int j = 0; j < 4; j++) acc[i][j] = (f32x4){0.f, 0.f, 0.f, 0.f};

    int pr   = t >> 3;                      // paired-row 0..63 within pass
    int slot = t & 7;
    int cg   = slot ^ (pr & 7);
    int srow = pr * 2 + (cg >> 2);          // 0..127 (+128 for pass 1)
    int scol = (cg & 3) * 8;                // f16 col within BK=32

    const ushort_t* gAh = Ah + (int64_t)(m0 + srow) * K + scol;
    const ushort_t* gAl = Al + (int64_t)(m0 + srow) * K + scol;
    const ushort_t* gB  = Bs + (int64_t)(n0 + srow) * K + scol;
    const int64_t rstep = (int64_t)128 * K;     // pass-1 global row offset

    auto stage_all = [&](int bufi, int kofs) {  // prologue only
        ushort_t* Lb = lds + bufi * 24576 + t * 8;
        ld16(gAh + kofs,         Lb);
        ld16(gAh + rstep + kofs, Lb + 4096);
        ld16(gAl + kofs,         Lb + 8192);
        ld16(gAl + rstep + kofs, Lb + 12288);
        ld16(gB  + kofs,         Lb + 16384);
        ld16(gB  + rstep + kofs, Lb + 20480);
    };

    int aoff[8], boff[4];
#pragma unroll
    for (int i = 0; i < 8; i++) {
        int R = wr + i * 16 + l15;
        int p = R >> 1, c = ((R & 1) << 2) + quad;
        aoff[i] = p * 64 + ((c ^ (p & 7)) << 3);
    }
#pragma unroll
    for (int j = 0; j < 4; j++) {
        int R = wc + j * 16 + l15;
        int p = R >> 1, c = ((R & 1) << 2) + quad;
        boff[j] = p * 64 + ((c ^ (p & 7)) << 3);
    }

    const int NT = 32;
    stage_all(0, 0);                        // prologue: tiles 0 and 1 in flight
    stage_all(1, 32);

    for (int kt = 0; kt < NT; ++kt) {
        const ushort_t* Lb = lds + (kt % 3) * 24576;
        ushort_t* Ld = lds + ((kt + 2) % 3) * 24576 + t * 8;
        const int nofs = (kt + 2) * 32;
        const bool pre = (kt + 2) < NT;

        if (kt + 1 < NT) {
            asm volatile("s_waitcnt vmcnt(6)" ::: "memory");
        } else {
            asm volatile("s_waitcnt vmcnt(0)" ::: "memory");
        }
        __builtin_amdgcn_s_barrier();
        asm volatile("" ::: "memory");
        __builtin_amdgcn_sched_barrier(0);

        half8 av[4], bf[4];

        // ---- phase 0: bf + ah(rh0); stage Ah(kt+2) ----
#pragma unroll
        for (int j = 0; j < 4; j++) bf[j] = *(const half8*)(Lb + 16384 + boff[j]);
#pragma unroll
        for (int i = 0; i < 4; i++) av[i] = *(const half8*)(Lb + aoff[i]);
        if (pre) { ld16(gAh + nofs, Ld);  ld16(gAh + rstep + nofs, Ld + 4096); }
        __builtin_amdgcn_s_barrier();
        __builtin_amdgcn_s_setprio(1);
#pragma unroll
        for (int i = 0; i < 4; i++)
#pragma unroll
            for (int j = 0; j < 4; j++)
                acc[i][j] = __builtin_amdgcn_mfma_f32_16x16x32_f16(av[i], bf[j], acc[i][j], 0, 0, 0);
        __builtin_amdgcn_s_setprio(0);
        __builtin_amdgcn_s_barrier();

        // ---- phase 1: al(rh0); stage Al(kt+2) ----
#pragma unroll
        for (int i = 0; i < 4; i++) av[i] = *(const half8*)(Lb + 8192 + aoff[i]);
        if (pre) { ld16(gAl + nofs, Ld + 8192);  ld16(gAl + rstep + nofs, Ld + 12288); }
        __builtin_amdgcn_s_barrier();
        __builtin_amdgcn_s_setprio(1);
#pragma unroll
        for (int i = 0; i < 4; i++)
#pragma unroll
            for (int j = 0; j < 4; j++)
                acc[i][j] = __builtin_amdgcn_mfma_f32_16x16x32_f16(av[i], bf[j], acc[i][j], 0, 0, 0);
        __builtin_amdgcn_s_setprio(0);
        __builtin_amdgcn_s_barrier();

        // ---- phase 2: ah(rh1); stage B(kt+2) ----
#pragma unroll
        for (int i = 0; i < 4; i++) av[i] = *(const half8*)(Lb + aoff[4 + i]);
        if (pre) { ld16(gB + nofs, Ld + 16384);  ld16(gB + rstep + nofs, Ld + 20480); }
        __builtin_amdgcn_s_barrier();
        __builtin_amdgcn_s_setprio(1);
#pragma unroll
        for (int i = 0; i < 4; i++)
#pragma unroll
            for (int j = 0; j < 4; j++)
                acc[4 + i][j] = __builtin_amdgcn_mfma_f32_16x16x32_f16(av[i], bf[j], acc[4 + i][j], 0, 0, 0);
        __builtin_amdgcn_s_setprio(0);
        __builtin_amdgcn_s_barrier();

        // ---- phase 3: al(rh1) ----  (tail barrier elided: next head has one)
#pragma unroll
        for (int i = 0; i < 4; i++) av[i] = *(const half8*)(Lb + 8192 + aoff[4 + i]);
        __builtin_amdgcn_s_barrier();
        __builtin_amdgcn_s_setprio(1);
#pragma unroll
        for (int i = 0; i < 4; i++)
#pragma unroll
            for (int j = 0; j < 4; j++)
                acc[4 + i][j] = __builtin_amdgcn_mfma_f32_16x16x32_f16(av[i], bf[j], acc[4 + i][j], 0, 0, 0);
        __builtin_amdgcn_s_setprio(0);
    }

    // C store (f32, coalesced per 16 lanes)
#pragma unroll
    for (int i = 0; i < 8; i++) {
        int row_base = m0 + wr + i * 16 + quad * 4;
#pragma unroll
        for (int j = 0; j < 4; j++) {
            int col = n0 + wc + j * 16 + l15;
#pragma unroll
            for (int r = 0; r < 4; r++)
                C[(int64_t)(row_base + r) * N + col] = acc[i][j][r];
        }
    }

    // fused partial column stats (max & sumexp over this block's 256 rows)
    int wrow = wave >> 2;                   // row-half of the block
#pragma unroll
    for (int j = 0; j < 4; j++) {
        float m = -3.0e38f;
#pragma unroll
        for (int i = 0; i < 8; i++)
#pragma unroll
            for (int r = 0; r < 4; r++) m = fmaxf(m, acc[i][j][r]);
        float s = 0.f;
#pragma unroll
        for (int i = 0; i < 8; i++)
#pragma unroll
            for (int r = 0; r < 4; r++) s += __expf(acc[i][j][r] - m);
#pragma unroll
        for (int d = 16; d <= 32; d <<= 1) {
            float m2 = __shfl_xor(m, d, 64);
            float s2 = __shfl_xor(s, d, 64);
            float nm = fmaxf(m, m2);
            s = s * __expf(m - nm) + s2 * __expf(m2 - nm);
            m = nm;
        }
        if (lane < 16) {
            red_m[wrow][wc + j * 16 + l15] = m;
            red_s[wrow][wc + j * 16 + l15] = s;
        }
    }
    __syncthreads();
    if (t < 256) {
        float ma = red_m[0][t], mb = red_m[1][t];
        float sa = red_s[0][t], sb = red_s[1][t];
        float m = fmaxf(ma, mb);
        float s = sa * __expf(ma - m) + sb * __expf(mb - m);
        int idx = by * (B_ * S_) + b * S_ + n0 + t;    // decoded by, not blockIdx.y
        pm[idx] = m;
        ps[idx] = s;
    }
}

// --------------------------- column softmax --------------------------------

__global__ void k_colstats2(const float* __restrict__ pm, const float* __restrict__ ps,
                            float* __restrict__ cmax, float* __restrict__ cinv)
{
    int i = blockIdx.x * 256 + threadIdx.x;   // 8192
    float m = -3.0e38f;
#pragma unroll
    for (int c = 0; c < 8; c++) m = fmaxf(m, pm[c * (B_ * S_) + i]);
    float sum = 0.f;
#pragma unroll
    for (int c = 0; c < 8; c++) sum += ps[c * (B_ * S_) + i] * __expf(pm[c * (B_ * S_) + i] - m);
    cmax[i] = m;
    cinv[i] = 1.0f / sum;
}

// weight = exp(L - cmax)/csum, in place; also emit f16 copy for the final GEMM
__global__ void k_softmax_norm(float4* __restrict__ L, const float4* __restrict__ cmax4,
                               const float4* __restrict__ cinv4, ushort4* __restrict__ wbf)
{
    const int64_t n4 = (int64_t)B_ * S_ * S_ / 4;
    for (int64_t i = (int64_t)blockIdx.x * blockDim.x + threadIdx.x; i < n4;
         i += (int64_t)gridDim.x * blockDim.x) {
        int b  = (int)(i >> 20);
        int c4 = (int)(i & 511);
        float4 x  = L[i];
        float4 cm = cmax4[b * 512 + c4];
        float4 ci = cinv4[b * 512 + c4];
        f32x4 w;
        w.x = __expf(x.x - cm.x) * ci.x;
        w.y = __expf(x.y - cm.y) * ci.y;
        w.z = __expf(x.z - cm.z) * ci.z;
        w.w = __expf(x.w - cm.w) * ci.w;
        __builtin_nontemporal_store(w, (f32x4*)&L[i]);  // w f32: never re-read
        wbf[i] = (ushort4){f2h(w.x), f2h(w.y), f2h(w.z), f2h(w.w)};
    }
}

// ---------------- dual NT f16 GEMM, 256x256 tiles (R14) ---------------------
// Two NT GEMMs (PT and Q) in one 256-block launch; C[m][n] = sum A[m][k]B[n][k].
// 256x256 tile, BK=32, 8 waves 2Mx4N of 128x64.  3-buf LDS (96KB), counted
// vmcnt(4), prefetch 2 deep, XOR chunk swizzle, 2 phases per K-tile of
// 16 MFMA each.  Per-half bijective XCD swizzle (A-panel sharers -> one XCD):
//   PT half (id<128):  g = (id&7) + 8*(id>>6), bx = (id>>3)&7   [M=1024,N=2048]
//   Q  half (id>=128): g = (i2&7) + 8*(i2>>5), bx = (i2>>3)&3   [M=2048,N=1024]
__launch_bounds__(512, 2)
__global__ void k_gemm_nt2(const ushort_t* __restrict__ A0, int lda0, int64_t bsA0,
                           const ushort_t* __restrict__ B0, int ldb0, int64_t bsB0,
                           ushort_t* __restrict__ C0, int ldc0, int64_t bsC0,
                           const ushort_t* __restrict__ A1, int lda1, int64_t bsA1,
                           const ushort_t* __restrict__ B1, int ldb1, int64_t bsB1,
                           ushort_t* __restrict__ C1, int ldc1, int64_t bsC1)
{
    const int K = D_;
    int id = blockIdx.x;
    const ushort_t *A, *Bm;
    ushort_t* C;
    int lda, ldb, ldc, bx, by;
    if (id < 128) {
        int g = (id & 7) + 8 * (id >> 6);           // 0..15
        bx = (id >> 3) & 7;                         // 0..7
        by = g & 3;                                 // 0..3
        int b = g >> 2;
        A = A0 + (int64_t)b * bsA0;  Bm = B0 + (int64_t)b * bsB0;  C = C0 + (int64_t)b * bsC0;
        lda = lda0; ldb = ldb0; ldc = ldc0;
    } else {
        int i2 = id - 128;
        int g = (i2 & 7) + 8 * (i2 >> 5);           // 0..31
        bx = (i2 >> 3) & 3;                         // 0..3
        by = g & 7;                                 // 0..7
        int b = g >> 3;
        A = A1 + (int64_t)b * bsA1;  Bm = B1 + (int64_t)b * bsB1;  C = C1 + (int64_t)b * bsC1;
        lda = lda1; ldb = ldb1; ldc = ldc1;
    }

    // 3 bufs x { A 16KB | B 16KB }  (ushort units; 96 KiB total)
    __shared__ __align__(16) ushort_t lds[3 * 16384];

    int t    = threadIdx.x;                 // 0..511
    int m0   = by * 256, n0 = bx * 256;
    int wave = t >> 6, lane = t & 63;
    int wr   = (wave >> 2) * 128;           // 0,128
    int wc   = (wave & 3) * 64;             // 0,64,128,192
    int l15  = lane & 15, quad = lane >> 4;

    f32x4 acc[8][4];
#pragma unroll
    for (int i = 0; i < 8; i++)
#pragma unroll
        for (int j = 0; j < 4; j++) acc[i][j] = (f32x4){0.f, 0.f, 0.f, 0.f};

    // staging map (paired-row [128][64] per 256x32 tile, swizzle inverted on
    // the global side; LDS dest linear at t*16B per 8KB pass)
    int pr   = t >> 3;
    int slot = t & 7;
    int cg   = slot ^ (pr & 7);
    int srow = pr * 2 + (cg >> 2);          // 0..127 (+128 for pass 1)
    int scol = (cg & 3) * 8;

    const ushort_t* gA = A  + (int64_t)(m0 + srow) * lda + scol;
    const ushort_t* gB = Bm + (int64_t)(n0 + srow) * ldb + scol;
    const int64_t rstepA = (int64_t)128 * lda;
    const int64_t rstepB = (int64_t)128 * ldb;

    auto stageA = [&](int bufi, int kofs) {
        ushort_t* Lb = lds + bufi * 16384 + t * 8;
        ld16(gA + kofs,          Lb);
        ld16(gA + rstepA + kofs, Lb + 4096);
    };
    auto stageB = [&](int bufi, int kofs) {
        ushort_t* Lb = lds + bufi * 16384 + t * 8;
        ld16(gB + kofs,          Lb + 8192);
        ld16(gB + rstepB + kofs, Lb + 12288);
    };

    int aoff[8], boff[4];
#pragma unroll
    for (int i = 0; i < 8; i++) {
        int R = wr + i * 16 + l15;
        int p = R >> 1, c = ((R & 1) << 2) + quad;
        aoff[i] = p * 64 + ((c ^ (p & 7)) << 3);
    }
#pragma unroll
    for (int j = 0; j < 4; j++) {
        int R = wc + j * 16 + l15;
        int p = R >> 1, c = ((R & 1) << 2) + quad;
        boff[j] = p * 64 + ((c ^ (p & 7)) << 3);
    }

    const int NT = K >> 5;                  // 32
    stageA(0, 0);  stageB(0, 0);            // prologue: tiles 0 and 1 in flight
    stageA(1, 32); stageB(1, 32);

    for (int kt = 0; kt < NT; ++kt) {
        const ushort_t* Lb = lds + (kt % 3) * 16384;
        const int buf2 = (kt + 2) % 3;
        const int nofs = (kt + 2) * 32;
        const bool pre = (kt + 2) < NT;

        if (kt + 1 < NT) {
            asm volatile("s_waitcnt vmcnt(4)" ::: "memory");
        } else {
            asm volatile("s_waitcnt vmcnt(0)" ::: "memory");
        }
        __builtin_amdgcn_s_barrier();
        asm volatile("" ::: "memory");
        __builtin_amdgcn_sched_barrier(0);

        half8 av[4], bf[4];

        // ---- phase 0: bf + a(rh0); stage A(kt+2) ----
#pragma unroll
        for (int j = 0; j < 4; j++) bf[j] = *(const half8*)(Lb + 8192 + boff[j]);
#pragma unroll
        for (int i = 0; i < 4; i++) av[i] = *(const half8*)(Lb + aoff[i]);
        if (pre) stageA(buf2, nofs);
        __builtin_amdgcn_s_barrier();
        __builtin_amdgcn_s_setprio(1);
#pragma unroll
        for (int i = 0; i < 4; i++)
#pragma unroll
            for (int j = 0; j < 4; j++)
                acc[i][j] = __builtin_amdgcn_mfma_f32_16x16x32_f16(av[i], bf[j], acc[i][j], 0, 0, 0);
        __builtin_amdgcn_s_setprio(0);
        __builtin_amdgcn_s_barrier();

        // ---- phase 1: a(rh1); stage B(kt+2) ----  (tail bar elided)
#pragma unroll
        for (int i = 0; i < 4; i++) av[i] = *(const half8*)(Lb + aoff[4 + i]);
        if (pre) stageB(buf2, nofs);
        __builtin_amdgcn_s_barrier();
        __builtin_amdgcn_s_setprio(1);
#pragma unroll
        for (int i = 0; i < 4; i++)
#pragma unroll
            for (int j = 0; j < 4; j++)
                acc[4 + i][j] = __builtin_amdgcn_mfma_f32_16x16x32_f16(av[i], bf[j], acc[4 + i][j], 0, 0, 0);
        __builtin_amdgcn_s_setprio(0);
    }

    // C store (f16)
#pragma unroll
    for (int i = 0; i < 8; i++) {
        int row_base = m0 + wr + i * 16 + quad * 4;
#pragma unroll
        for (int j = 0; j < 4; j++) {
            int col = n0 + wc + j * 16 + l15;
#pragma unroll
            for (int r = 0; r < 4; r++)
                C[(int64_t)(row_base + r) * ldc + col] = f2h(acc[i][j][r]);
        }
    }
}

// --------------------------- final GEMM -------------------------------------
// out[b][t][n] = sum_s weight_f16[b][t][s]*PT[b][n][s] + Q[b][t][n] + bias[n]
// 256x128 / BK=64 / 8-wave, 3-buf counted vmcnt(6), 2-phase interleave.
// XCD swizzle: wg = (g&7) + 8*bx + 64*(g>>3), g = by + 8*b.
__launch_bounds__(512, 2)
__global__ void k_gemm_final(const ushort_t* __restrict__ Wt, const ushort_t* __restrict__ PT,
                             const ushort_t* __restrict__ Q, const float* __restrict__ bias,
                             float* __restrict__ out)
{
    const int K = S_, N = OUTD;
    int wg = blockIdx.x + 8 * blockIdx.y + 64 * blockIdx.z;   // 0..255
    int bx = (wg >> 3) & 7;
    int g  = (wg & 7) + 8 * (wg >> 6);
    int by = g & 7;
    int b  = g >> 3;

    const ushort_t* A  = Wt + (int64_t)b * S_ * S_;
    const ushort_t* Bm = PT + (int64_t)b * OUTD * S_;
    const ushort_t* Qb = Q  + (int64_t)b * S_ * OUTD;
    float* Cb = out + (int64_t)b * S_ * OUTD;

    __shared__ __align__(16) ushort_t lds[3 * 24576];

    int t    = threadIdx.x;
    int m0   = by * 256, n0 = bx * 128;
    int wave = t >> 6, lane = t & 63;
    int wr   = (wave >> 1) * 64;
    int wc   = (wave & 1) * 64;
    int l15  = lane & 15, quad = lane >> 4;

    f32x4 acc[4][4];
#pragma unroll
    for (int i = 0; i < 4; i++)
#pragma unroll
        for (int j = 0; j < 4; j++) acc[i][j] = (f32x4){0.f, 0.f, 0.f, 0.f};

    int srow = t >> 3;
    int cg   = (t & 7) ^ (srow & 7);
    int scol = cg * 8;

    const ushort_t* gA = A  + (int64_t)(m0 + srow) * K + scol;
    const ushort_t* gB = Bm + (int64_t)(n0 + srow) * K + scol;

    auto stage = [&](int bufi, int k0) {    // prologue only
        ushort_t* Lb = lds + bufi * 24576 + t * 8;
        ld16(gA + k0,                      Lb);
        ld16(gA + (int64_t)64  * K + k0,   Lb + 4096);
        ld16(gA + (int64_t)128 * K + k0,   Lb + 8192);
        ld16(gA + (int64_t)192 * K + k0,   Lb + 12288);
        ld16(gB + k0,                      Lb + 16384);
        ld16(gB + (int64_t)64  * K + k0,   Lb + 20480);
    };

    int aoff[4][2], boff[4][2];
#pragma unroll
    for (int i = 0; i < 4; i++) {
        int R = wr + i * 16 + l15;
#pragma unroll
        for (int h = 0; h < 2; h++) {
            int c = quad + h * 4;
            aoff[i][h] = R * 64 + ((c ^ (R & 7)) << 3);
        }
    }
#pragma unroll
    for (int j = 0; j < 4; j++) {
        int R = wc + j * 16 + l15;
#pragma unroll
        for (int h = 0; h < 2; h++) {
            int c = quad + h * 4;
            boff[j][h] = 16384 + R * 64 + ((c ^ (R & 7)) << 3);
        }
    }

    const int NT = K >> 6;                  // 32
    stage(0, 0);
    stage(1, 64);

    for (int kt = 0; kt < NT; ++kt) {
        const ushort_t* Lb = lds + (kt % 3) * 24576;
        ushort_t* Ld = lds + ((kt + 2) % 3) * 24576 + t * 8;
        const int nofs = (kt + 2) * 64;
        const bool pre = (kt + 2) < NT;

        if (kt + 1 < NT) {
            asm volatile("s_waitcnt vmcnt(6)" ::: "memory");
        } else {
            asm volatile("s_waitcnt vmcnt(0)" ::: "memory");
        }
        __builtin_amdgcn_s_barrier();
        asm volatile("" ::: "memory");
        __builtin_amdgcn_sched_barrier(0);

        half8 af[4], bf[4];

        // ---- phase 0 (h=0) ----
#pragma unroll
        for (int i = 0; i < 4; i++) af[i] = *(const half8*)(Lb + aoff[i][0]);
#pragma unroll
        for (int j = 0; j < 4; j++) bf[j] = *(const half8*)(Lb + boff[j][0]);
        if (pre) {
            ld16(gA + nofs,                    Ld);
            ld16(gA + (int64_t)64  * K + nofs, Ld + 4096);
            ld16(gA + (int64_t)128 * K + nofs, Ld + 8192);
        }
        __builtin_amdgcn_s_barrier();
        __builtin_amdgcn_s_setprio(1);
#pragma unroll
        for (int i = 0; i < 4; i++)
#pragma unroll
            for (int j = 0; j < 4; j++)
                acc[i][j] = __builtin_amdgcn_mfma_f32_16x16x32_f16(af[i], bf[j], acc[i][j], 0, 0, 0);
        __builtin_amdgcn_s_setprio(0);
        __builtin_amdgcn_s_barrier();

        // ---- phase 1 (h=1) ----
#pragma unroll
        for (int i = 0; i < 4; i++) af[i] = *(const half8*)(Lb + aoff[i][1]);
#pragma unroll
        for (int j = 0; j < 4; j++) bf[j] = *(const half8*)(Lb + boff[j][1]);
        if (pre) {
            ld16(gA + (int64_t)192 * K + nofs, Ld + 12288);
            ld16(gB + nofs,                    Ld + 16384);
            ld16(gB + (int64_t)64  * K + nofs, Ld + 20480);
        }
        __builtin_amdgcn_s_barrier();
        __builtin_amdgcn_s_setprio(1);
#pragma unroll
        for (int i = 0; i < 4; i++)
#pragma unroll
            for (int j = 0; j < 4; j++)
                acc[i][j] = __builtin_amdgcn_mfma_f32_16x16x32_f16(af[i], bf[j], acc[i][j], 0, 0, 0);
        __builtin_amdgcn_s_setprio(0);
        // tail barrier elided: next iteration head has one
    }

#pragma unroll
    for (int i = 0; i < 4; i++) {
        int row_base = m0 + wr + i * 16 + quad * 4;
#pragma unroll
        for (int j = 0; j < 4; j++) {
            int col = n0 + wc + j * 16 + l15;
            float bv = bias[col];
#pragma unroll
            for (int r = 0; r < 4; r++) {
                int64_t idx = (int64_t)(row_base + r) * N + col;
                float v = acc[i][j][r] + h2f(Qb[idx]) + bv;
                __builtin_nontemporal_store(v, &Cb[idx]);   // out: never re-read
            }
        }
    }
}

// ------------------------------- launcher ----------------------------------

extern "C" void kernel_launch(void* const* d_in, const int* in_sizes, int n_in,
                              void* d_out, int out_size, void* d_ws, size_t ws_size,
                              hipStream_t stream)
{
    const float* src  = (const float*)d_in[0];
    const float* tgt  = (const float*)d_in[1];
    const float* W    = (const float*)d_in[2];
    const float* bias = (const float*)d_in[3];

    float* out = (float*)d_out;                           // [4,2048,1024]
    float* Lw  = out + (size_t)B_ * S_ * OUTD;            // [4,2048,2048] logits -> weight

    char*  ws = (char*)d_ws;
    size_t o  = 0;
    auto take = [&](size_t bytes) -> char* {
        char* p = ws + o;
        o += (bytes + 255) & ~(size_t)255;
        return p;
    };
    const size_t ELEMS = (size_t)B_ * S_ * D_;            // 8,388,608
    ushort_t* sh   = (ushort_t*)take(ELEMS * 2);          // src f16
    ushort_t* th   = (ushort_t*)take(ELEMS * 2);          // tgt hi f16
    ushort_t* tl   = (ushort_t*)take(ELEMS * 2);          // tgt lo f16
    ushort_t* wbf  = (ushort_t*)take((size_t)B_ * S_ * S_ * 2);     // weight f16
    ushort_t* wb   = (ushort_t*)take((size_t)OUTD * 2 * D_ * 2);    // W f16 [1024,2048]
    ushort_t* PT   = (ushort_t*)take((size_t)B_ * OUTD * S_ * 2);   // W1@src^T f16 [b,1024,2048]
    ushort_t* Qb   = (ushort_t*)take((size_t)B_ * S_ * OUTD * 2);   // tgt@W2^T f16 [b,2048,1024]
    float*    pm   = (float*)take(16 * (size_t)B_ * S_ * 4);
    float*    ps   = (float*)take(16 * (size_t)B_ * S_ * 4);
    float*    cmax = (float*)take((size_t)B_ * S_ * 4);
    float*    cinv = (float*)take((size_t)B_ * S_ * 4);
    (void)ws_size; (void)in_sizes; (void)n_in; (void)out_size;

    // fused: src/tgt f16 split + W f16 convert
    k_split<<<dim3(2560), dim3(256), 0, stream>>>(
        (const float4*)src, (const float4*)tgt, (const float4*)W,
        (ushort4*)sh, (ushort4*)th, (ushort4*)tl, (ushort4*)wb);

    // dual GEMM, 256x256 tiles: PT (blocks 0..127), Q (blocks 128..255)
    k_gemm_nt2<<<dim3(256), dim3(512), 0, stream>>>(
        wb, 2 * D_, 0,  sh, D_, (int64_t)S_ * D_,  PT, S_, (int64_t)OUTD * S_,
        th, D_, (int64_t)S_ * D_,  wb + D_, 2 * D_, 0,  Qb, OUTD, (int64_t)S_ * OUTD);

    k_gemm_logits<<<dim3(8, 8, 4), dim3(512), 0, stream>>>(th, tl, sh, Lw, pm, ps);

    k_colstats2<<<dim3(32), dim3(256), 0, stream>>>(pm, ps, cmax, cinv);
    k_softmax_norm<<<dim3(2048), dim3(256), 0, stream>>>((float4*)Lw, (const float4*)cmax,
                                                         (const float4*)cinv, (ushort4*)wbf);

    k_gemm_final<<<dim3(8, 8, 4), dim3(512), 0, stream>>>(wbf, PT, Qb, bias, out);
}